// Round 1
// baseline (9781.800 us; speedup 1.0000x reference)
//
#include <hip/hip_runtime.h>
#include <hip/hip_bf16.h>
#include <math.h>

// Problem constants
#define B_ 2
#define S_ 2048
#define DIM_ 4096
#define H_ 32
#define KV_ 8
#define HD_ 128
#define REP_ 4
#define SCALE_ 0.08838834764831844f  // 128^-0.5

// ---------------------------------------------------------------------------
// Tiled fp32 GEMM: C = A(MxK) @ W(KxN), both row-major.
// LAYOUT 0: C row-major [M][N]
// LAYOUT 1: head-major:  m=(b*S_+s), n=(h*HD_+d) -> C[((b*heads+h)*S_+s)*HD_+d]
// Tile 128x128, K-step 16, 256 threads, 8x8 micro-tile, double-buffered LDS.
// All dims here are exact multiples of tile sizes (4096/1024) — no bounds checks.
// ---------------------------------------------------------------------------
template <int LAYOUT>
__global__ __launch_bounds__(256) void gemm_f32(
    const float* __restrict__ A, const float* __restrict__ W,
    float* __restrict__ C, int M, int N, int K, int heads) {
  __shared__ float As[2][16][132];  // transposed A tile, padded (132%4==0 keeps 16B align)
  __shared__ float Bs[2][16][128];

  const int tid = threadIdx.x;
  const int tx = tid & 15, ty = tid >> 4;
  const int row0 = blockIdx.y * 128;
  const int col0 = blockIdx.x * 128;

  float acc[8][8];
#pragma unroll
  for (int i = 0; i < 8; ++i)
#pragma unroll
    for (int j = 0; j < 8; ++j) acc[i][j] = 0.f;

  float4 ra[2], rb[2];

  auto g_load = [&](int kt) {
    const int k0 = kt * 16;
#pragma unroll
    for (int u = 0; u < 2; ++u) {
      int id = tid * 2 + u;
      int r = id >> 2, c4 = id & 3;  // A: 128 rows x 4 float4
      ra[u] = *(const float4*)(A + (size_t)(row0 + r) * K + k0 + c4 * 4);
      int kr = id >> 5, c4b = id & 31;  // B: 16 rows x 32 float4
      rb[u] = *(const float4*)(W + (size_t)(k0 + kr) * N + col0 + c4b * 4);
    }
  };
  auto l_store = [&](int buf) {
#pragma unroll
    for (int u = 0; u < 2; ++u) {
      int id = tid * 2 + u;
      int r = id >> 2, c4 = id & 3;
      As[buf][c4 * 4 + 0][r] = ra[u].x;
      As[buf][c4 * 4 + 1][r] = ra[u].y;
      As[buf][c4 * 4 + 2][r] = ra[u].z;
      As[buf][c4 * 4 + 3][r] = ra[u].w;
      int kr = id >> 5, c4b = id & 31;
      *(float4*)&Bs[buf][kr][c4b * 4] = rb[u];
    }
  };

  g_load(0);
  l_store(0);
  __syncthreads();

  const int nk = K >> 4;
  for (int kt = 0; kt < nk; ++kt) {
    const int cur = kt & 1;
    if (kt + 1 < nk) g_load(kt + 1);
#pragma unroll
    for (int kk = 0; kk < 16; ++kk) {
      float4 a0 = *(const float4*)&As[cur][kk][ty * 8];
      float4 a1 = *(const float4*)&As[cur][kk][ty * 8 + 4];
      float4 b0 = *(const float4*)&Bs[cur][kk][tx * 8];
      float4 b1 = *(const float4*)&Bs[cur][kk][tx * 8 + 4];
      float av[8] = {a0.x, a0.y, a0.z, a0.w, a1.x, a1.y, a1.z, a1.w};
      float bv[8] = {b0.x, b0.y, b0.z, b0.w, b1.x, b1.y, b1.z, b1.w};
#pragma unroll
      for (int i = 0; i < 8; ++i)
#pragma unroll
        for (int j = 0; j < 8; ++j) acc[i][j] = fmaf(av[i], bv[j], acc[i][j]);
    }
    if (kt + 1 < nk) {
      // Safe: prior iteration's __syncthreads guarantees nobody still reads buf cur^1.
      l_store(cur ^ 1);
      __syncthreads();
    }
  }

#pragma unroll
  for (int i = 0; i < 8; ++i) {
    int m = row0 + ty * 8 + i;
#pragma unroll
    for (int j4 = 0; j4 < 2; ++j4) {
      int n = col0 + tx * 8 + j4 * 4;
      float4 v = make_float4(acc[i][j4 * 4 + 0], acc[i][j4 * 4 + 1],
                             acc[i][j4 * 4 + 2], acc[i][j4 * 4 + 3]);
      if (LAYOUT == 0) {
        *(float4*)(C + (size_t)m * N + n) = v;
      } else {
        int b = m >> 11, s = m & (S_ - 1);
        int h = n >> 7, d = n & (HD_ - 1);
        *(float4*)(C + ((size_t)(b * heads + h) * S_ + s) * HD_ + d) = v;
      }
    }
  }
}

// ---------------------------------------------------------------------------
// RoPE in-place on [B*heads, S, HD]; pair (2i, 2i+1), angle row = s.
// ---------------------------------------------------------------------------
__global__ __launch_bounds__(256) void rope_f32(float* __restrict__ T,
                                                const float* __restrict__ cs,
                                                const float* __restrict__ sn,
                                                int total) {
  int idx = blockIdx.x * 256 + threadIdx.x;
  if (idx >= total) return;
  int i = idx & 63;
  int s = (idx >> 6) & (S_ - 1);
  int bh = idx >> 17;  // 64*2048 = 2^17
  float c = cs[s * 64 + i], si = sn[s * 64 + i];
  float2* p = (float2*)(T + ((size_t)bh * S_ + s) * HD_) + i;
  float2 v = *p;
  *p = make_float2(v.x * c - v.y * si, v.x * si + v.y * c);
}

// ---------------------------------------------------------------------------
// Flash-style causal GQA attention, fp32.
// Q: [B,H,S,HD], K/V: [B,KV,S,HD], O: [B,S,H,HD].
// Block: 256 threads (16x16). QTILE=64, KVTILE=64.
// Thread (tx,ty): score micro-tile rows ty*4+i / cols tx*4+j,
//                 O micro-tile   rows ty*4+i / cols tx*8+j (same rows!).
// Row stats (m,l) live in registers, replicated across the 16 tx lanes.
// ---------------------------------------------------------------------------
__global__ __launch_bounds__(256) void attn_f32(const float* __restrict__ Q,
                                                const float* __restrict__ Kb,
                                                const float* __restrict__ Vb,
                                                float* __restrict__ O) {
  __shared__ float Qs[64][132];
  __shared__ float KVs[64][132];
  __shared__ float Ps[64][68];

  const int tid = threadIdx.x;
  const int tx = tid & 15, ty = tid >> 4;
  const int qt = blockIdx.x, h = blockIdx.y, b = blockIdx.z;
  const int kvh = h >> 2;  // REP_=4
  const int q0 = qt * 64;

  const float* Qbase = Q + ((size_t)(b * H_ + h) * S_ + q0) * HD_;
  const float* Kbase = Kb + ((size_t)(b * KV_ + kvh) * S_) * HD_;
  const float* Vbase = Vb + ((size_t)(b * KV_ + kvh) * S_) * HD_;

  for (int i = tid; i < 64 * 32; i += 256) {
    int r = i >> 5, c4 = i & 31;
    *(float4*)&Qs[r][c4 * 4] = *(const float4*)(Qbase + (size_t)r * HD_ + c4 * 4);
  }

  float oacc[4][8];
  float mrow[4], lrow[4];
#pragma unroll
  for (int i = 0; i < 4; ++i) {
    mrow[i] = -3.0e38f;
    lrow[i] = 0.f;
#pragma unroll
    for (int j = 0; j < 8; ++j) oacc[i][j] = 0.f;
  }
  __syncthreads();

  for (int kt = 0; kt <= qt; ++kt) {
    // ---- K tile -> KVs
    for (int i = tid; i < 64 * 32; i += 256) {
      int r = i >> 5, c4 = i & 31;
      *(float4*)&KVs[r][c4 * 4] =
          *(const float4*)(Kbase + (size_t)(kt * 64 + r) * HD_ + c4 * 4);
    }
    __syncthreads();

    // ---- scores S = scale * Q K^T (4x4 per thread)
    float sacc[4][4];
#pragma unroll
    for (int i = 0; i < 4; ++i)
#pragma unroll
      for (int j = 0; j < 4; ++j) sacc[i][j] = 0.f;

#pragma unroll 4
    for (int d4 = 0; d4 < 32; ++d4) {
      float4 qa[4], kb[4];
#pragma unroll
      for (int i = 0; i < 4; ++i) qa[i] = *(const float4*)&Qs[ty * 4 + i][d4 * 4];
#pragma unroll
      for (int j = 0; j < 4; ++j) kb[j] = *(const float4*)&KVs[tx * 4 + j][d4 * 4];
#pragma unroll
      for (int i = 0; i < 4; ++i)
#pragma unroll
        for (int j = 0; j < 4; ++j) {
          sacc[i][j] = fmaf(qa[i].x, kb[j].x, sacc[i][j]);
          sacc[i][j] = fmaf(qa[i].y, kb[j].y, sacc[i][j]);
          sacc[i][j] = fmaf(qa[i].z, kb[j].z, sacc[i][j]);
          sacc[i][j] = fmaf(qa[i].w, kb[j].w, sacc[i][j]);
        }
    }

    const bool diag = (kt == qt);
#pragma unroll
    for (int i = 0; i < 4; ++i)
#pragma unroll
      for (int j = 0; j < 4; ++j) {
        float s = sacc[i][j] * SCALE_;
        if (diag) {
          int sk = kt * 64 + tx * 4 + j, sq = q0 + ty * 4 + i;
          if (sk > sq) s = -3.0e38f;
        }
        sacc[i][j] = s;
      }

    // ---- online softmax (row groups = 16 consecutive lanes, shfl_xor reduce)
#pragma unroll
    for (int i = 0; i < 4; ++i) {
      float v = fmaxf(fmaxf(sacc[i][0], sacc[i][1]), fmaxf(sacc[i][2], sacc[i][3]));
#pragma unroll
      for (int off = 1; off < 16; off <<= 1) v = fmaxf(v, __shfl_xor(v, off, 64));
      float mnew = fmaxf(mrow[i], v);
      float f = __expf(mrow[i] - mnew);
      float psum = 0.f;
#pragma unroll
      for (int j = 0; j < 4; ++j) {
        float p = __expf(sacc[i][j] - mnew);
        sacc[i][j] = p;
        psum += p;
      }
#pragma unroll
      for (int off = 1; off < 16; off <<= 1) psum += __shfl_xor(psum, off, 64);
      lrow[i] = lrow[i] * f + psum;
      mrow[i] = mnew;
#pragma unroll
      for (int j = 0; j < 8; ++j) oacc[i][j] *= f;
    }

#pragma unroll
    for (int i = 0; i < 4; ++i)
      *(float4*)&Ps[ty * 4 + i][tx * 4] =
          make_float4(sacc[i][0], sacc[i][1], sacc[i][2], sacc[i][3]);
    __syncthreads();  // P written; K reads done -> reuse KVs for V

    // ---- V tile -> KVs
    for (int i = tid; i < 64 * 32; i += 256) {
      int r = i >> 5, c4 = i & 31;
      *(float4*)&KVs[r][c4 * 4] =
          *(const float4*)(Vbase + (size_t)(kt * 64 + r) * HD_ + c4 * 4);
    }
    __syncthreads();

    // ---- O += P @ V
#pragma unroll 4
    for (int k = 0; k < 64; ++k) {
      float4 v0 = *(const float4*)&KVs[k][tx * 8];
      float4 v1 = *(const float4*)&KVs[k][tx * 8 + 4];
#pragma unroll
      for (int i = 0; i < 4; ++i) {
        float p = Ps[ty * 4 + i][k];
        oacc[i][0] = fmaf(p, v0.x, oacc[i][0]);
        oacc[i][1] = fmaf(p, v0.y, oacc[i][1]);
        oacc[i][2] = fmaf(p, v0.z, oacc[i][2]);
        oacc[i][3] = fmaf(p, v0.w, oacc[i][3]);
        oacc[i][4] = fmaf(p, v1.x, oacc[i][4]);
        oacc[i][5] = fmaf(p, v1.y, oacc[i][5]);
        oacc[i][6] = fmaf(p, v1.z, oacc[i][6]);
        oacc[i][7] = fmaf(p, v1.w, oacc[i][7]);
      }
    }
    __syncthreads();  // KVs/Ps free for next tile
  }

  // ---- epilogue: O[b, s, h, :] = oacc / l
#pragma unroll
  for (int i = 0; i < 4; ++i) {
    int sq = q0 + ty * 4 + i;
    float inv = 1.f / lrow[i];
    float* dst = O + ((size_t)(b * S_ + sq) * H_ + h) * HD_ + tx * 8;
    *(float4*)dst = make_float4(oacc[i][0] * inv, oacc[i][1] * inv,
                                oacc[i][2] * inv, oacc[i][3] * inv);
    *(float4*)(dst + 4) = make_float4(oacc[i][4] * inv, oacc[i][5] * inv,
                                      oacc[i][6] * inv, oacc[i][7] * inv);
  }
}

// ---------------------------------------------------------------------------
extern "C" void kernel_launch(void* const* d_in, const int* in_sizes, int n_in,
                              void* d_out, int out_size, void* d_ws, size_t ws_size,
                              hipStream_t stream) {
  const float* x  = (const float*)d_in[0];
  const float* wq = (const float*)d_in[1];
  const float* wk = (const float*)d_in[2];
  const float* wv = (const float*)d_in[3];
  const float* wo = (const float*)d_in[4];
  const float* fc = (const float*)d_in[5];
  const float* fs = (const float*)d_in[6];
  // d_in[7] = mask (implied by causal), d_in[8] = positions (== arange(S)) — unused.
  float* out = (float*)d_out;

  // Workspace layout (needs 160 MiB):
  //   Q  [B,H,S,HD]  64 MiB
  //   K  [B,KV,S,HD] 16 MiB
  //   V  [B,KV,S,HD] 16 MiB
  //   AO [B,S,H*HD]  64 MiB
  float* Q  = (float*)d_ws;
  float* Kb = Q + (size_t)B_ * H_ * S_ * HD_;
  float* Vb = Kb + (size_t)B_ * KV_ * S_ * HD_;
  float* AO = Vb + (size_t)B_ * KV_ * S_ * HD_;

  const int M = B_ * S_;  // 4096
  dim3 blk(256);

  gemm_f32<1><<<dim3(DIM_ / 128, M / 128), blk, 0, stream>>>(x, wq, Q, M, H_ * HD_, DIM_, H_);
  gemm_f32<1><<<dim3((KV_ * HD_) / 128, M / 128), blk, 0, stream>>>(x, wk, Kb, M, KV_ * HD_, DIM_, KV_);
  gemm_f32<1><<<dim3((KV_ * HD_) / 128, M / 128), blk, 0, stream>>>(x, wv, Vb, M, KV_ * HD_, DIM_, KV_);

  rope_f32<<<dim3((B_ * H_ * S_ * 64) / 256), blk, 0, stream>>>(Q, fc, fs, B_ * H_ * S_ * 64);
  rope_f32<<<dim3((B_ * KV_ * S_ * 64) / 256), blk, 0, stream>>>(Kb, fc, fs, B_ * KV_ * S_ * 64);

  attn_f32<<<dim3(S_ / 64, H_, B_), blk, 0, stream>>>(Q, Kb, Vb, AO);

  gemm_f32<0><<<dim3(DIM_ / 128, M / 128), blk, 0, stream>>>(AO, wo, out, M, DIM_, H_ * HD_, 0);
}

// Round 3
// 890.133 us; speedup vs baseline: 10.9892x; 10.9892x over previous
//
#include <hip/hip_runtime.h>
#include <math.h>

#define B_ 2
#define S_ 2048
#define DIM_ 4096
#define H_ 32
#define KV_ 8
#define HD_ 128
#define SCALE_ 0.08838834764831844f  // 128^-0.5

typedef unsigned short u16;
typedef __attribute__((ext_vector_type(8))) short bf16x8;
typedef __attribute__((ext_vector_type(4))) float f32x4;
typedef __attribute__((ext_vector_type(8))) unsigned short u16x8;
typedef __attribute__((ext_vector_type(4))) unsigned short u16x4;

__device__ __forceinline__ u16 f2b(float f) {  // RNE f32->bf16
  union { float f; unsigned u; } v; v.f = f;
  unsigned r = v.u + 0x7fffu + ((v.u >> 16) & 1u);
  return (u16)(r >> 16);
}
__device__ __forceinline__ float b2f(u16 h) {
  union { unsigned u; float f; } v; v.u = ((unsigned)h) << 16;
  return v.f;
}
// Direct-to-LDS async copy, 16B/lane. LDS dest = wave-uniform base + lane*16.
__device__ __forceinline__ void async_copy16(const void* g, void* l) {
  __builtin_amdgcn_global_load_lds(
      (const __attribute__((address_space(1))) void*)g,
      (__attribute__((address_space(3))) void*)l, 16, 0, 0);
}

// ---------------------------------------------------------------------------
// fp32 -> bf16 bulk convert (vectorized)
// ---------------------------------------------------------------------------
__global__ __launch_bounds__(256) void cvt_bf16(const float* __restrict__ in,
                                                u16* __restrict__ out, int n4) {
  int i = blockIdx.x * 256 + threadIdx.x;
  if (i >= n4) return;
  float4 v = ((const float4*)in)[i];
  u16x4 o; o[0] = f2b(v.x); o[1] = f2b(v.y); o[2] = f2b(v.z); o[3] = f2b(v.w);
  ((u16x4*)out)[i] = o;
}

// ---------------------------------------------------------------------------
// W[K][N] fp32 -> WT[N][K] bf16  (tiled 64x64 via LDS)
// ---------------------------------------------------------------------------
__global__ __launch_bounds__(256) void transpose_cvt(
    const float* __restrict__ W, u16* __restrict__ WT, int K, int N) {
  __shared__ float Ts[64][65];
  const int tid = threadIdx.x;
  const int n0 = blockIdx.x * 64, k0 = blockIdx.y * 64;
#pragma unroll
  for (int p = 0; p < 4; ++p) {
    int r = p * 16 + (tid >> 4), c = (tid & 15) * 4;
    float4 v = *(const float4*)(W + (size_t)(k0 + r) * N + n0 + c);
    Ts[r][c] = v.x; Ts[r][c + 1] = v.y; Ts[r][c + 2] = v.z; Ts[r][c + 3] = v.w;
  }
  __syncthreads();
#pragma unroll
  for (int p = 0; p < 4; ++p) {
    int n = p * 16 + (tid >> 4), kq = (tid & 15) * 4;
    u16x4 o;
    o[0] = f2b(Ts[kq + 0][n]); o[1] = f2b(Ts[kq + 1][n]);
    o[2] = f2b(Ts[kq + 2][n]); o[3] = f2b(Ts[kq + 3][n]);
    *(u16x4*)(WT + (size_t)(n0 + n) * K + k0 + kq) = o;
  }
}

// ---------------------------------------------------------------------------
// V [B*KV][S][HD] bf16 -> Vt [B*KV][HD][S] bf16 (tiled 64x64)
// ---------------------------------------------------------------------------
__global__ __launch_bounds__(256) void transpose_v(const u16* __restrict__ V,
                                                   u16* __restrict__ Vt) {
  __shared__ u16 Ts[64][72];
  const int tid = threadIdx.x;
  const int s0 = blockIdx.x * 64, d0 = blockIdx.y * 64, hb = blockIdx.z;
  const u16* src = V + ((size_t)hb * S_ + s0) * HD_ + d0;
#pragma unroll
  for (int p = 0; p < 2; ++p) {
    int r = p * 32 + (tid >> 3), seg = (tid & 7) * 8;
    u16x8 v = *(const u16x8*)(src + (size_t)r * HD_ + seg);
#pragma unroll
    for (int j = 0; j < 8; ++j) Ts[r][seg + j] = v[j];
  }
  __syncthreads();
  u16* dst = Vt + ((size_t)hb * HD_ + d0) * S_ + s0;
#pragma unroll
  for (int p = 0; p < 2; ++p) {
    int d = p * 32 + (tid >> 3), seg = (tid & 7) * 8;
    u16x8 o;
#pragma unroll
    for (int j = 0; j < 8; ++j) o[j] = Ts[seg + j][d];
    *(u16x8*)(dst + (size_t)d * S_ + seg) = o;
  }
}

// ---------------------------------------------------------------------------
// RoPE in-place on bf16 head-major [BH][S][HD]; idx enumerates (bh,s,pair).
// ---------------------------------------------------------------------------
__global__ __launch_bounds__(256) void rope_bf16(unsigned* __restrict__ T,
                                                 const float* __restrict__ cs,
                                                 const float* __restrict__ sn,
                                                 int total) {
  int idx = blockIdx.x * 256 + threadIdx.x;
  if (idx >= total) return;
  int i = idx & 63, s = (idx >> 6) & (S_ - 1);
  float c = cs[s * 64 + i], si = sn[s * 64 + i];
  unsigned v = T[idx];
  float re = b2f((u16)(v & 0xffffu)), im = b2f((u16)(v >> 16));
  float ore = re * c - im * si, oim = re * si + im * c;
  T[idx] = (unsigned)f2b(ore) | ((unsigned)f2b(oim) << 16);
}

// ---------------------------------------------------------------------------
// bf16 MFMA GEMM, m97 structure. C = A[M][K] @ Bt[N][K]^T, fp32 accum.
// 128x128 tile, BK=64, 4 waves (64x64 each), 16x16x32 MFMA.
// LDS tiles XOR-swizzled (seg ^ (row&7), 16B granules) via pre-swizzled
// global source (global_load_lds writes linearly) -> conflict-free ds_read_b128.
// OUT_MODE 0: fp32 row-major. OUT_MODE 1: bf16 head-major [B,heads,S,HD].
// ---------------------------------------------------------------------------
template <int OUT_MODE>
__global__ __launch_bounds__(256) void gemm_bf16(
    const u16* __restrict__ A, const u16* __restrict__ Bt,
    void* __restrict__ Cout, int M, int N, int K, int heads) {
  __shared__ u16 As[128 * 64];
  __shared__ u16 Bs[128 * 64];
  const int tid = threadIdx.x, lane = tid & 63;
  const int wbase = tid & ~63;  // wave-uniform
  const int row0 = blockIdx.y * 128, col0 = blockIdx.x * 128;
  const int wm = ((tid >> 6) >> 1) * 64, wn = ((tid >> 6) & 1) * 64;

  f32x4 acc[4][4];
#pragma unroll
  for (int i = 0; i < 4; ++i)
#pragma unroll
    for (int j = 0; j < 4; ++j) acc[i][j] = (f32x4){0.f, 0.f, 0.f, 0.f};

  const int nk = K >> 6;
  for (int kt = 0; kt < nk; ++kt) {
    const int k0 = kt << 6;
#pragma unroll
    for (int i = 0; i < 4; ++i) {  // A tile: 128 rows x 128B (8 granules/row)
      int g = i * 256 + tid;
      int r = g >> 3, ss = (g & 7) ^ (r & 7);
      async_copy16(A + (size_t)(row0 + r) * K + k0 + ss * 8,
                   (char*)As + (i * 256 + wbase) * 16);
    }
#pragma unroll
    for (int i = 0; i < 4; ++i) {  // B tile (Bt rows = output cols)
      int g = i * 256 + tid;
      int r = g >> 3, ss = (g & 7) ^ (r & 7);
      async_copy16(Bt + (size_t)(col0 + r) * K + k0 + ss * 8,
                   (char*)Bs + (i * 256 + wbase) * 16);
    }
    __syncthreads();
#pragma unroll
    for (int ks = 0; ks < 2; ++ks) {
      bf16x8 af[4], bf[4];
#pragma unroll
      for (int mi = 0; mi < 4; ++mi) {
        int r = wm + mi * 16 + (lane & 15);
        int off = (ks * 64 + ((lane >> 4) << 4)) ^ ((r & 7) << 4);
        af[mi] = *(const bf16x8*)((const char*)As + r * 128 + off);
      }
#pragma unroll
      for (int ni = 0; ni < 4; ++ni) {
        int r = wn + ni * 16 + (lane & 15);
        int off = (ks * 64 + ((lane >> 4) << 4)) ^ ((r & 7) << 4);
        bf[ni] = *(const bf16x8*)((const char*)Bs + r * 128 + off);
      }
#pragma unroll
      for (int mi = 0; mi < 4; ++mi)
#pragma unroll
        for (int ni = 0; ni < 4; ++ni)
          acc[mi][ni] = __builtin_amdgcn_mfma_f32_16x16x32_bf16(
              af[mi], bf[ni], acc[mi][ni], 0, 0, 0);
    }
    __syncthreads();
  }

  // epilogue: D layout col=lane&15, row=(lane>>4)*4+r  [HW-verified m89/m91]
#pragma unroll
  for (int mi = 0; mi < 4; ++mi)
#pragma unroll
    for (int ni = 0; ni < 4; ++ni) {
      int mb = row0 + wm + mi * 16 + ((lane >> 4) << 2);
      int n = col0 + wn + ni * 16 + (lane & 15);
#pragma unroll
      for (int r = 0; r < 4; ++r) {
        int m = mb + r;
        float v = acc[mi][ni][r];
        if (OUT_MODE == 0) {
          ((float*)Cout)[(size_t)m * N + n] = v;
        } else {
          int b = m >> 11, s = m & (S_ - 1);
          int h = n >> 7, d = n & (HD_ - 1);
          ((u16*)Cout)[(((size_t)(b * heads + h)) * S_ + s) * HD_ + d] = f2b(v);
        }
      }
    }
}

// ---------------------------------------------------------------------------
// Flash attention, bf16 MFMA, fp32 online softmax.
// Q [B,H,S,HD] bf16, K [B,KV,S,HD] bf16, Vt [B,KV,HD,S] bf16,
// AO [B,S,H*HD] bf16. Block: 256 thr (4 waves), Q-tile 64 (16 rows/wave),
// KV-tile 64. All LDS tiles XOR-swizzled -> conflict-free ds_read_b128.
// ---------------------------------------------------------------------------
__global__ __launch_bounds__(256) void attn_mfma(
    const u16* __restrict__ Qb, const u16* __restrict__ Kb,
    const u16* __restrict__ Vt, u16* __restrict__ AO) {
  __shared__ u16 Ks[64 * 128];    // [s][d] 256B rows, swizzled
  __shared__ u16 Vs[128 * 64];    // [d][s] 128B rows, swizzled
  __shared__ u16 Ps[4][16 * 64];  // per-wave P [q][k], 128B rows, swizzled

  const int tid = threadIdx.x, lane = tid & 63, wid = tid >> 6;
  const int wbase = tid & ~63;
  const int qt = blockIdx.x, h = blockIdx.y, b = blockIdx.z;
  const int q0 = qt * 64;
  const int kvh = h >> 2;  // REP=4

  const u16* Qbase = Qb + ((size_t)(b * H_ + h) * S_ + q0) * HD_;
  const u16* Kbase = Kb + ((size_t)(b * KV_ + kvh) * S_) * HD_;
  const u16* Vbase = Vt + ((size_t)(b * KV_ + kvh) * HD_) * S_;

  // Q fragments in registers: wave wid owns q rows wid*16..+15
  bf16x8 qf[4];
  {
    const u16* qrow =
        Qbase + (size_t)(wid * 16 + (lane & 15)) * HD_ + ((lane >> 4) << 3);
#pragma unroll
    for (int ks = 0; ks < 4; ++ks) qf[ks] = *(const bf16x8*)(qrow + ks * 32);
  }

  f32x4 oacc[8];
#pragma unroll
  for (int i = 0; i < 8; ++i) oacc[i] = (f32x4){0.f, 0.f, 0.f, 0.f};
  float mrow[4] = {-3e38f, -3e38f, -3e38f, -3e38f};
  float lrow[4] = {0.f, 0.f, 0.f, 0.f};

  for (int kt = 0; kt <= qt; ++kt) {
    const int kv0 = kt * 64;
#pragma unroll
    for (int i = 0; i < 4; ++i) {  // K tile: 64 rows x 256B (16 granules/row)
      int g = i * 256 + tid;
      int r = g >> 4, ss = (g & 15) ^ (r & 7);
      async_copy16(Kbase + (size_t)(kv0 + r) * HD_ + ss * 8,
                   (char*)Ks + (i * 256 + wbase) * 16);
    }
#pragma unroll
    for (int i = 0; i < 4; ++i) {  // V tile: 128 rows x 128B (8 granules/row)
      int g = i * 256 + tid;
      int r = g >> 3, ss = (g & 7) ^ (r & 7);
      async_copy16(Vbase + (size_t)r * S_ + kv0 + ss * 8,
                   (char*)Vs + (i * 256 + wbase) * 16);
    }
    __syncthreads();

    // ---- S = Q K^T  (per wave: 16q x 64k, 4 n-frags x 4 k-steps)
    f32x4 sacc[4];
#pragma unroll
    for (int nf = 0; nf < 4; ++nf) sacc[nf] = (f32x4){0.f, 0.f, 0.f, 0.f};
#pragma unroll
    for (int nf = 0; nf < 4; ++nf) {
      int r = nf * 16 + (lane & 15);
      const char* base = (const char*)Ks + r * 256;
#pragma unroll
      for (int ks = 0; ks < 4; ++ks) {
        int off = (ks * 64 + ((lane >> 4) << 4)) ^ ((r & 7) << 4);
        bf16x8 kf = *(const bf16x8*)(base + off);
        sacc[nf] =
            __builtin_amdgcn_mfma_f32_16x16x32_bf16(qf[ks], kf, sacc[nf], 0, 0, 0);
      }
    }

    // ---- mask + online softmax (fp32). Lane holds S[(lane>>4)*4+r][nf*16+(lane&15)]
    const bool diag = (kt == qt);
#pragma unroll
    for (int r = 0; r < 4; ++r) {
      int qg = q0 + wid * 16 + ((lane >> 4) << 2) + r;
      float rowmax = -3e38f;
#pragma unroll
      for (int nf = 0; nf < 4; ++nf) {
        float sv = sacc[nf][r] * SCALE_;
        if (diag && (kv0 + nf * 16 + (lane & 15)) > qg) sv = -3e38f;
        sacc[nf][r] = sv;
        rowmax = fmaxf(rowmax, sv);
      }
#pragma unroll
      for (int off = 1; off < 16; off <<= 1)
        rowmax = fmaxf(rowmax, __shfl_xor(rowmax, off, 64));
      float mnew = fmaxf(mrow[r], rowmax);
      float fsc = __expf(mrow[r] - mnew);
      mrow[r] = mnew;
      float psum = 0.f;
#pragma unroll
      for (int nf = 0; nf < 4; ++nf) {
        float p = __expf(sacc[nf][r] - mnew);
        sacc[nf][r] = p;
        psum += p;
      }
#pragma unroll
      for (int off = 1; off < 16; off <<= 1) psum += __shfl_xor(psum, off, 64);
      lrow[r] = lrow[r] * fsc + psum;
#pragma unroll
      for (int df = 0; df < 8; ++df) oacc[df][r] *= fsc;
    }

    // ---- P -> per-wave LDS (bf16, swizzled); same-wave RAW, compiler waits
    char* pw = (char*)Ps[wid];
#pragma unroll
    for (int nf = 0; nf < 4; ++nf)
#pragma unroll
      for (int r = 0; r < 4; ++r) {
        int q = ((lane >> 4) << 2) + r;
        int col = nf * 16 + (lane & 15);
        int byte = q * 128 + ((((col >> 3) ^ (q & 7)) << 4)) + ((col & 7) << 1);
        *(u16*)(pw + byte) = f2b(sacc[nf][r]);
      }

    // ---- O += P @ V  (8 d-frags x 2 k-steps)
#pragma unroll
    for (int ks = 0; ks < 2; ++ks) {
      int q = lane & 15;
      int poff = q * 128 + ((ks * 64 + ((lane >> 4) << 4)) ^ ((q & 7) << 4));
      bf16x8 pf = *(const bf16x8*)(pw + poff);
#pragma unroll
      for (int df = 0; df < 8; ++df) {
        int vr = df * 16 + (lane & 15);
        int voff = (ks * 64 + ((lane >> 4) << 4)) ^ ((vr & 7) << 4);
        bf16x8 vf = *(const bf16x8*)((const char*)Vs + vr * 128 + voff);
        oacc[df] =
            __builtin_amdgcn_mfma_f32_16x16x32_bf16(pf, vf, oacc[df], 0, 0, 0);
      }
    }
    __syncthreads();  // all waves done with Ks/Vs before next staging
  }

  float inv[4];
#pragma unroll
  for (int r = 0; r < 4; ++r) inv[r] = 1.f / lrow[r];
#pragma unroll
  for (int df = 0; df < 8; ++df)
#pragma unroll
    for (int r = 0; r < 4; ++r) {
      int sq = q0 + wid * 16 + ((lane >> 4) << 2) + r;
      AO[(size_t)(b * S_ + sq) * (H_ * HD_) + h * HD_ + df * 16 + (lane & 15)] =
          f2b(oacc[df][r] * inv[r]);
    }
}

// ---------------------------------------------------------------------------
extern "C" void kernel_launch(void* const* d_in, const int* in_sizes, int n_in,
                              void* d_out, int out_size, void* d_ws, size_t ws_size,
                              hipStream_t stream) {
  const float* x  = (const float*)d_in[0];
  const float* wq = (const float*)d_in[1];
  const float* wk = (const float*)d_in[2];
  const float* wv = (const float*)d_in[3];
  const float* wo = (const float*)d_in[4];
  const float* fc = (const float*)d_in[5];
  const float* fs = (const float*)d_in[6];
  float* out = (float*)d_out;

  // Workspace (u16 elements), total exactly 160 MiB (proven available R1):
  //   [0        ) wqT 16.7M   -- dead after Q-GEMM; reused for Vt (4.2M)
  //   [16777216 ) xb  16.7M   -- dead after V-GEMM; reused for AOb
  //   [33554432 ) woT 16.7M
  //   [50331648 ) Qh  16.7M
  //   [67108864 ) wkT 4.2M
  //   [71303168 ) wvT 4.2M
  //   [75497472 ) Kh  4.2M
  //   [79691776 ) Vh  4.2M    -> end 83886080 u16 = 160 MiB
  u16* ws  = (u16*)d_ws;
  u16* wqT = ws;
  u16* VtB = ws;              // alias of wqT region (after wqT last use)
  u16* xb  = ws + 16777216;
  u16* AOb = xb;              // alias of xb region (after xb last use)
  u16* woT = ws + 33554432;
  u16* Qh  = ws + 50331648;
  u16* wkT = ws + 67108864;
  u16* wvT = ws + 71303168;
  u16* Kh  = ws + 75497472;
  u16* Vh  = ws + 79691776;

  dim3 blk(256);

  cvt_bf16<<<dim3(16384), blk, 0, stream>>>(x, xb, 4194304);
  transpose_cvt<<<dim3(64, 64), blk, 0, stream>>>(wq, wqT, DIM_, H_ * HD_);
  transpose_cvt<<<dim3(16, 64), blk, 0, stream>>>(wk, wkT, DIM_, KV_ * HD_);
  transpose_cvt<<<dim3(16, 64), blk, 0, stream>>>(wv, wvT, DIM_, KV_ * HD_);
  transpose_cvt<<<dim3(64, 64), blk, 0, stream>>>(wo, woT, H_ * HD_, DIM_);

  gemm_bf16<1><<<dim3(32, 32), blk, 0, stream>>>(xb, wqT, Qh, 4096, 4096, 4096, H_);
  gemm_bf16<1><<<dim3(8, 32), blk, 0, stream>>>(xb, wkT, Kh, 4096, 1024, 4096, KV_);
  gemm_bf16<1><<<dim3(8, 32), blk, 0, stream>>>(xb, wvT, Vh, 4096, 1024, 4096, KV_);

  rope_bf16<<<dim3(32768), blk, 0, stream>>>((unsigned*)Qh, fc, fs, 8388608);
  rope_bf16<<<dim3(8192), blk, 0, stream>>>((unsigned*)Kh, fc, fs, 2097152);

  transpose_v<<<dim3(32, 2, 16), blk, 0, stream>>>(Vh, VtB);

  attn_mfma<<<dim3(32, 32, 2), blk, 0, stream>>>(Qh, Kh, VtB, AOb);

  gemm_bf16<0><<<dim3(32, 32), blk, 0, stream>>>(AOb, woT, out, 4096, 4096, 4096, 0);
}

// Round 4
// 749.888 us; speedup vs baseline: 13.0443x; 1.1870x over previous
//
#include <hip/hip_runtime.h>
#include <math.h>

#define B_ 2
#define S_ 2048
#define DIM_ 4096
#define H_ 32
#define KV_ 8
#define HD_ 128
#define SCALE_ 0.08838834764831844f   // 128^-0.5
#define QSCALE_ 0.12751744154254998f  // SCALE_ * log2(e)

typedef unsigned short u16;
typedef __attribute__((ext_vector_type(8))) short bf16x8;
typedef __attribute__((ext_vector_type(4))) float f32x4;
typedef __attribute__((ext_vector_type(8))) unsigned short u16x8;
typedef __attribute__((ext_vector_type(4))) unsigned short u16x4;

__device__ __forceinline__ u16 f2b(float f) {  // RNE f32->bf16
  union { float f; unsigned u; } v; v.f = f;
  unsigned r = v.u + 0x7fffu + ((v.u >> 16) & 1u);
  return (u16)(r >> 16);
}
__device__ __forceinline__ float b2f(u16 h) {
  union { unsigned u; float f; } v; v.u = ((unsigned)h) << 16;
  return v.f;
}
// Direct-to-LDS async copy, 16B/lane. LDS dest = wave-uniform base + lane*16.
__device__ __forceinline__ void async_copy16(const void* g, void* l) {
  __builtin_amdgcn_global_load_lds(
      (const __attribute__((address_space(1))) void*)g,
      (__attribute__((address_space(3))) void*)l, 16, 0, 0);
}

// ---------------------------------------------------------------------------
// fp32 -> bf16 bulk convert (vectorized)
// ---------------------------------------------------------------------------
__global__ __launch_bounds__(256) void cvt_bf16(const float* __restrict__ in,
                                                u16* __restrict__ out, int n4) {
  int i = blockIdx.x * 256 + threadIdx.x;
  if (i >= n4) return;
  float4 v = ((const float4*)in)[i];
  u16x4 o; o[0] = f2b(v.x); o[1] = f2b(v.y); o[2] = f2b(v.z); o[3] = f2b(v.w);
  ((u16x4*)out)[i] = o;
}

// ---------------------------------------------------------------------------
// W[K][N] fp32 -> WT[N][K] bf16  (tiled 64x64 via LDS)
// ---------------------------------------------------------------------------
__global__ __launch_bounds__(256) void transpose_cvt(
    const float* __restrict__ W, u16* __restrict__ WT, int K, int N) {
  __shared__ float Ts[64][65];
  const int tid = threadIdx.x;
  const int n0 = blockIdx.x * 64, k0 = blockIdx.y * 64;
#pragma unroll
  for (int p = 0; p < 4; ++p) {
    int r = p * 16 + (tid >> 4), c = (tid & 15) * 4;
    float4 v = *(const float4*)(W + (size_t)(k0 + r) * N + n0 + c);
    Ts[r][c] = v.x; Ts[r][c + 1] = v.y; Ts[r][c + 2] = v.z; Ts[r][c + 3] = v.w;
  }
  __syncthreads();
#pragma unroll
  for (int p = 0; p < 4; ++p) {
    int n = p * 16 + (tid >> 4), kq = (tid & 15) * 4;
    u16x4 o;
    o[0] = f2b(Ts[kq + 0][n]); o[1] = f2b(Ts[kq + 1][n]);
    o[2] = f2b(Ts[kq + 2][n]); o[3] = f2b(Ts[kq + 3][n]);
    *(u16x4*)(WT + (size_t)(n0 + n) * K + k0 + kq) = o;
  }
}

// ---------------------------------------------------------------------------
// V [B*KV][S][HD] bf16 -> Vt [B*KV][HD][S] bf16 (tiled 64x64)
// ---------------------------------------------------------------------------
__global__ __launch_bounds__(256) void transpose_v(const u16* __restrict__ V,
                                                   u16* __restrict__ Vt) {
  __shared__ u16 Ts[64][72];
  const int tid = threadIdx.x;
  const int s0 = blockIdx.x * 64, d0 = blockIdx.y * 64, hb = blockIdx.z;
  const u16* src = V + ((size_t)hb * S_ + s0) * HD_ + d0;
#pragma unroll
  for (int p = 0; p < 2; ++p) {
    int r = p * 32 + (tid >> 3), seg = (tid & 7) * 8;
    u16x8 v = *(const u16x8*)(src + (size_t)r * HD_ + seg);
#pragma unroll
    for (int j = 0; j < 8; ++j) Ts[r][seg + j] = v[j];
  }
  __syncthreads();
  u16* dst = Vt + ((size_t)hb * HD_ + d0) * S_ + s0;
#pragma unroll
  for (int p = 0; p < 2; ++p) {
    int d = p * 32 + (tid >> 3), seg = (tid & 7) * 8;
    u16x8 o;
#pragma unroll
    for (int j = 0; j < 8; ++j) o[j] = Ts[seg + j][d];
    *(u16x8*)(dst + (size_t)d * S_ + seg) = o;
  }
}

// ---------------------------------------------------------------------------
// RoPE in-place on bf16 head-major [BH][S][HD], with output scale folded in.
// (Q gets SCALE*log2e so attention can use exp2 directly; K gets 1.0.)
// ---------------------------------------------------------------------------
__global__ __launch_bounds__(256) void rope_bf16(unsigned* __restrict__ T,
                                                 const float* __restrict__ cs,
                                                 const float* __restrict__ sn,
                                                 int total, float scale) {
  int idx = blockIdx.x * 256 + threadIdx.x;
  if (idx >= total) return;
  int i = idx & 63, s = (idx >> 6) & (S_ - 1);
  float c = cs[s * 64 + i], si = sn[s * 64 + i];
  unsigned v = T[idx];
  float re = b2f((u16)(v & 0xffffu)), im = b2f((u16)(v >> 16));
  float ore = (re * c - im * si) * scale, oim = (re * si + im * c) * scale;
  T[idx] = (unsigned)f2b(ore) | ((unsigned)f2b(oim) << 16);
}

// ---------------------------------------------------------------------------
// bf16 MFMA GEMM, m97 structure (unchanged from R3 — known-good).
// ---------------------------------------------------------------------------
template <int OUT_MODE>
__global__ __launch_bounds__(256) void gemm_bf16(
    const u16* __restrict__ A, const u16* __restrict__ Bt,
    void* __restrict__ Cout, int M, int N, int K, int heads) {
  __shared__ u16 As[128 * 64];
  __shared__ u16 Bs[128 * 64];
  const int tid = threadIdx.x, lane = tid & 63;
  const int wbase = tid & ~63;
  const int row0 = blockIdx.y * 128, col0 = blockIdx.x * 128;
  const int wm = ((tid >> 6) >> 1) * 64, wn = ((tid >> 6) & 1) * 64;

  f32x4 acc[4][4];
#pragma unroll
  for (int i = 0; i < 4; ++i)
#pragma unroll
    for (int j = 0; j < 4; ++j) acc[i][j] = (f32x4){0.f, 0.f, 0.f, 0.f};

  const int nk = K >> 6;
  for (int kt = 0; kt < nk; ++kt) {
    const int k0 = kt << 6;
#pragma unroll
    for (int i = 0; i < 4; ++i) {
      int g = i * 256 + tid;
      int r = g >> 3, ss = (g & 7) ^ (r & 7);
      async_copy16(A + (size_t)(row0 + r) * K + k0 + ss * 8,
                   (char*)As + (i * 256 + wbase) * 16);
    }
#pragma unroll
    for (int i = 0; i < 4; ++i) {
      int g = i * 256 + tid;
      int r = g >> 3, ss = (g & 7) ^ (r & 7);
      async_copy16(Bt + (size_t)(col0 + r) * K + k0 + ss * 8,
                   (char*)Bs + (i * 256 + wbase) * 16);
    }
    __syncthreads();
#pragma unroll
    for (int ks = 0; ks < 2; ++ks) {
      bf16x8 af[4], bf[4];
#pragma unroll
      for (int mi = 0; mi < 4; ++mi) {
        int r = wm + mi * 16 + (lane & 15);
        int off = (ks * 64 + ((lane >> 4) << 4)) ^ ((r & 7) << 4);
        af[mi] = *(const bf16x8*)((const char*)As + r * 128 + off);
      }
#pragma unroll
      for (int ni = 0; ni < 4; ++ni) {
        int r = wn + ni * 16 + (lane & 15);
        int off = (ks * 64 + ((lane >> 4) << 4)) ^ ((r & 7) << 4);
        bf[ni] = *(const bf16x8*)((const char*)Bs + r * 128 + off);
      }
#pragma unroll
      for (int mi = 0; mi < 4; ++mi)
#pragma unroll
        for (int ni = 0; ni < 4; ++ni)
          acc[mi][ni] = __builtin_amdgcn_mfma_f32_16x16x32_bf16(
              af[mi], bf[ni], acc[mi][ni], 0, 0, 0);
    }
    __syncthreads();
  }

#pragma unroll
  for (int mi = 0; mi < 4; ++mi)
#pragma unroll
    for (int ni = 0; ni < 4; ++ni) {
      int mb = row0 + wm + mi * 16 + ((lane >> 4) << 2);
      int n = col0 + wn + ni * 16 + (lane & 15);
#pragma unroll
      for (int r = 0; r < 4; ++r) {
        int m = mb + r;
        float v = acc[mi][ni][r];
        if (OUT_MODE == 0) {
          ((float*)Cout)[(size_t)m * N + n] = v;
        } else {
          int b = m >> 11, s = m & (S_ - 1);
          int h = n >> 7, d = n & (HD_ - 1);
          ((u16*)Cout)[(((size_t)(b * heads + h)) * S_ + s) * HD_ + d] = f2b(v);
        }
      }
    }
}

// ---------------------------------------------------------------------------
// Flash attention, bf16 MFMA. Swapped QK^T: sacc = mfma(K,Q) = S^T, so each
// lane owns ONE q-row (q = lane&15) with 16 k-values in registers ->
// in-register softmax (2 shfl_xor for cross-group combine). Q pre-scaled by
// SCALE*log2e in RoPE -> exp2f directly. P packed 4-k per ds_write_b64.
// Causal balance: block processes q-tiles {pid, 31-pid} -> uniform 33 k-tiles;
// grid 1024 blocks = 4/CU (40KB LDS) -> fully resident.
// ---------------------------------------------------------------------------
__global__ __launch_bounds__(256) void attn_mfma(
    const u16* __restrict__ Qb, const u16* __restrict__ Kb,
    const u16* __restrict__ Vt, u16* __restrict__ AO) {
  __shared__ u16 Ks[64 * 128];    // [s][d] 256B rows, swizzled
  __shared__ u16 Vs[128 * 64];    // [d][s] 128B rows, swizzled
  __shared__ u16 Ps[4][16 * 64];  // per-wave P [q][k], 128B rows, swizzled

  const int tid = threadIdx.x, lane = tid & 63, wid = tid >> 6;
  const int wbase = tid & ~63;
  const int pid = blockIdx.x, h = blockIdx.y, b = blockIdx.z;
  const int kvh = h >> 2;  // REP=4
  const int qq = lane & 15, g = lane >> 4;

  const u16* Kbase = Kb + ((size_t)(b * KV_ + kvh) * S_) * HD_;
  const u16* Vbase = Vt + ((size_t)(b * KV_ + kvh) * HD_) * S_;

  // Hoisted per-lane staging pointers (advance by kv0 per tile)
  const u16* Kl[4];
  const u16* Vl[4];
#pragma unroll
  for (int i = 0; i < 4; ++i) {
    int gg = i * 256 + tid;
    int rK = gg >> 4, ssK = (gg & 15) ^ (rK & 7);
    Kl[i] = Kbase + (size_t)rK * HD_ + ssK * 8;
    int rV = gg >> 3, ssV = (gg & 7) ^ (rV & 7);
    Vl[i] = Vbase + (size_t)rV * S_ + ssV * 8;
  }
  char* const pw = (char*)Ps[wid];

  for (int half = 0; half < 2; ++half) {
    const int qt = half ? (31 - pid) : pid;
    const int q0 = qt * 64;

    // Q fragments (pre-scaled by SCALE*log2e in rope): wave owns rows wid*16..+15
    bf16x8 qf[4];
    {
      const u16* qrow = Qb + ((size_t)(b * H_ + h) * S_ + q0 + wid * 16 + qq) * HD_ +
                        (g << 3);
#pragma unroll
      for (int ks = 0; ks < 4; ++ks) qf[ks] = *(const bf16x8*)(qrow + ks * 32);
    }

    f32x4 oacc[8];
#pragma unroll
    for (int i = 0; i < 8; ++i) oacc[i] = (f32x4){0.f, 0.f, 0.f, 0.f};
    float mrow = -3e38f, lrow = 0.f;

    for (int kt = 0; kt <= qt; ++kt) {
      const int kv0 = kt * 64;
#pragma unroll
      for (int i = 0; i < 4; ++i)
        async_copy16(Kl[i] + (size_t)kv0 * HD_, (char*)Ks + (i * 256 + wbase) * 16);
#pragma unroll
      for (int i = 0; i < 4; ++i)
        async_copy16(Vl[i] + kv0, (char*)Vs + (i * 256 + wbase) * 16);
      __syncthreads();

      // ---- S^T = K Q^T  (lane: 16 k-values for q = lane&15)
      f32x4 sacc[4];
#pragma unroll
      for (int nf = 0; nf < 4; ++nf) sacc[nf] = (f32x4){0.f, 0.f, 0.f, 0.f};
#pragma unroll
      for (int nf = 0; nf < 4; ++nf) {
        int r = nf * 16 + qq;
        const char* base = (const char*)Ks + r * 256;
#pragma unroll
        for (int ks = 0; ks < 4; ++ks) {
          int off = (ks * 64 + (g << 4)) ^ ((r & 7) << 4);
          bf16x8 kf = *(const bf16x8*)(base + off);
          sacc[nf] =
              __builtin_amdgcn_mfma_f32_16x16x32_bf16(kf, qf[ks], sacc[nf], 0, 0, 0);
        }
      }

      // ---- in-register online softmax (log2 domain); lane's k = nf*16+g*4+r
      float rmax = -3e38f;
      if (kt == qt) {
        const int qg = q0 + wid * 16 + qq;
#pragma unroll
        for (int nf = 0; nf < 4; ++nf)
#pragma unroll
          for (int r = 0; r < 4; ++r) {
            int kg = kv0 + nf * 16 + g * 4 + r;
            float sv = (kg > qg) ? -3e38f : sacc[nf][r];
            sacc[nf][r] = sv;
            rmax = fmaxf(rmax, sv);
          }
      } else {
#pragma unroll
        for (int nf = 0; nf < 4; ++nf)
#pragma unroll
          for (int r = 0; r < 4; ++r) rmax = fmaxf(rmax, sacc[nf][r]);
      }
      rmax = fmaxf(rmax, __shfl_xor(rmax, 16, 64));
      rmax = fmaxf(rmax, __shfl_xor(rmax, 32, 64));
      const float mnew = fmaxf(mrow, rmax);
      const float fsc = exp2f(mrow - mnew);
      mrow = mnew;
      float psum = 0.f;
#pragma unroll
      for (int nf = 0; nf < 4; ++nf)
#pragma unroll
        for (int r = 0; r < 4; ++r) {
          float p = exp2f(sacc[nf][r] - mnew);
          sacc[nf][r] = p;
          psum += p;
        }
      psum += __shfl_xor(psum, 16, 64);
      psum += __shfl_xor(psum, 32, 64);
      lrow = lrow * fsc + psum;

      // redistribute rescale factor to PV-accumulator rows (q = g*4+r)
      const float fr0 = __shfl(fsc, g * 4 + 0);
      const float fr1 = __shfl(fsc, g * 4 + 1);
      const float fr2 = __shfl(fsc, g * 4 + 2);
      const float fr3 = __shfl(fsc, g * 4 + 3);
#pragma unroll
      for (int df = 0; df < 8; ++df) {
        oacc[df][0] *= fr0; oacc[df][1] *= fr1;
        oacc[df][2] *= fr2; oacc[df][3] *= fr3;
      }

      // ---- P -> per-wave LDS: lane writes its 4-consecutive-k quads (b64)
#pragma unroll
      for (int nf = 0; nf < 4; ++nf) {
        u16x4 pk;
#pragma unroll
        for (int r = 0; r < 4; ++r) pk[r] = f2b(sacc[nf][r]);
        int gran = (nf * 2 + (g >> 1)) ^ (qq & 7);
        *(u16x4*)(pw + qq * 128 + gran * 16 + (g & 1) * 8) = pk;
      }

      // ---- O += P @ V  (8 d-frags x 2 k-steps); same-wave RAW on Ps
#pragma unroll
      for (int ks = 0; ks < 2; ++ks) {
        int poff = qq * 128 + ((ks * 64 + (g << 4)) ^ ((qq & 7) << 4));
        bf16x8 pf = *(const bf16x8*)(pw + poff);
#pragma unroll
        for (int df = 0; df < 8; ++df) {
          int vr = df * 16 + qq;
          int voff = (ks * 64 + (g << 4)) ^ ((vr & 7) << 4);
          bf16x8 vf = *(const bf16x8*)((const char*)Vs + vr * 128 + voff);
          oacc[df] =
              __builtin_amdgcn_mfma_f32_16x16x32_bf16(pf, vf, oacc[df], 0, 0, 0);
        }
      }
      __syncthreads();  // all waves done with Ks/Vs before next staging
    }

    // ---- epilogue: O rows q = g*4+r, cols d = df*16+qq
    const float linv = 1.f / lrow;
    const float i0 = __shfl(linv, g * 4 + 0);
    const float i1 = __shfl(linv, g * 4 + 1);
    const float i2 = __shfl(linv, g * 4 + 2);
    const float i3 = __shfl(linv, g * 4 + 3);
    const float inv[4] = {i0, i1, i2, i3};
#pragma unroll
    for (int df = 0; df < 8; ++df)
#pragma unroll
      for (int r = 0; r < 4; ++r) {
        int sq = q0 + wid * 16 + g * 4 + r;
        AO[(size_t)(b * S_ + sq) * (H_ * HD_) + h * HD_ + df * 16 + qq] =
            f2b(oacc[df][r] * inv[r]);
      }
  }
}

// ---------------------------------------------------------------------------
extern "C" void kernel_launch(void* const* d_in, const int* in_sizes, int n_in,
                              void* d_out, int out_size, void* d_ws, size_t ws_size,
                              hipStream_t stream) {
  const float* x  = (const float*)d_in[0];
  const float* wq = (const float*)d_in[1];
  const float* wk = (const float*)d_in[2];
  const float* wv = (const float*)d_in[3];
  const float* wo = (const float*)d_in[4];
  const float* fc = (const float*)d_in[5];
  const float* fs = (const float*)d_in[6];
  float* out = (float*)d_out;

  // Workspace (u16 elements), 160 MiB total — same layout as R3.
  u16* ws  = (u16*)d_ws;
  u16* wqT = ws;
  u16* VtB = ws;              // alias of wqT region (after wqT last use)
  u16* xb  = ws + 16777216;
  u16* AOb = xb;              // alias of xb region (after xb last use)
  u16* woT = ws + 33554432;
  u16* Qh  = ws + 50331648;
  u16* wkT = ws + 67108864;
  u16* wvT = ws + 71303168;
  u16* Kh  = ws + 75497472;
  u16* Vh  = ws + 79691776;

  dim3 blk(256);

  cvt_bf16<<<dim3(16384), blk, 0, stream>>>(x, xb, 4194304);
  transpose_cvt<<<dim3(64, 64), blk, 0, stream>>>(wq, wqT, DIM_, H_ * HD_);
  transpose_cvt<<<dim3(16, 64), blk, 0, stream>>>(wk, wkT, DIM_, KV_ * HD_);
  transpose_cvt<<<dim3(16, 64), blk, 0, stream>>>(wv, wvT, DIM_, KV_ * HD_);
  transpose_cvt<<<dim3(64, 64), blk, 0, stream>>>(wo, woT, H_ * HD_, DIM_);

  gemm_bf16<1><<<dim3(32, 32), blk, 0, stream>>>(xb, wqT, Qh, 4096, 4096, 4096, H_);
  gemm_bf16<1><<<dim3(8, 32), blk, 0, stream>>>(xb, wkT, Kh, 4096, 1024, 4096, KV_);
  gemm_bf16<1><<<dim3(8, 32), blk, 0, stream>>>(xb, wvT, Vh, 4096, 1024, 4096, KV_);

  rope_bf16<<<dim3(32768), blk, 0, stream>>>((unsigned*)Qh, fc, fs, 8388608, QSCALE_);
  rope_bf16<<<dim3(8192), blk, 0, stream>>>((unsigned*)Kh, fc, fs, 2097152, 1.0f);

  transpose_v<<<dim3(32, 2, 16), blk, 0, stream>>>(Vh, VtB);

  attn_mfma<<<dim3(16, 32, 2), blk, 0, stream>>>(Qh, Kh, VtB, AOb);

  gemm_bf16<0><<<dim3(32, 32), blk, 0, stream>>>(AOb, woT, out, 4096, 4096, 4096, 0);
}

// Round 6
// 666.206 us; speedup vs baseline: 14.6829x; 1.1256x over previous
//
#include <hip/hip_runtime.h>
#include <math.h>

#define B_ 2
#define S_ 2048
#define DIM_ 4096
#define H_ 32
#define KV_ 8
#define HD_ 128
#define SCALE_ 0.08838834764831844f   // 128^-0.5
#define QSCALE_ 0.12751744154254998f  // SCALE_ * log2(e)

typedef unsigned short u16;
typedef __attribute__((ext_vector_type(8))) short bf16x8;
typedef __attribute__((ext_vector_type(4))) float f32x4;
typedef __attribute__((ext_vector_type(8))) unsigned short u16x8;
typedef __attribute__((ext_vector_type(4))) unsigned short u16x4;

__device__ __forceinline__ u16 f2b(float f) {  // RNE f32->bf16
  union { float f; unsigned u; } v; v.f = f;
  unsigned r = v.u + 0x7fffu + ((v.u >> 16) & 1u);
  return (u16)(r >> 16);
}
__device__ __forceinline__ float b2f(u16 h) {
  union { unsigned u; float f; } v; v.u = ((unsigned)h) << 16;
  return v.f;
}
// Direct-to-LDS async copy, 16B/lane. LDS dest = wave-uniform base + lane*16.
__device__ __forceinline__ void async_copy16(const void* g, void* l) {
  __builtin_amdgcn_global_load_lds(
      (const __attribute__((address_space(1))) void*)g,
      (__attribute__((address_space(3))) void*)l, 16, 0, 0);
}
// Raw barrier WITH compiler memory fence (no vmcnt drain, unlike __syncthreads)
__device__ __forceinline__ void bar() {
  asm volatile("s_barrier" ::: "memory");
}

// ---------------------------------------------------------------------------
// fp32 -> bf16 bulk convert (vectorized)
// ---------------------------------------------------------------------------
__global__ __launch_bounds__(256) void cvt_bf16(const float* __restrict__ in,
                                                u16* __restrict__ out, int n4) {
  int i = blockIdx.x * 256 + threadIdx.x;
  if (i >= n4) return;
  float4 v = ((const float4*)in)[i];
  u16x4 o; o[0] = f2b(v.x); o[1] = f2b(v.y); o[2] = f2b(v.z); o[3] = f2b(v.w);
  ((u16x4*)out)[i] = o;
}

// ---------------------------------------------------------------------------
// W[K][N] fp32 -> WT[N][K] bf16  (tiled 64x64 via LDS)
// ---------------------------------------------------------------------------
__global__ __launch_bounds__(256) void transpose_cvt(
    const float* __restrict__ W, u16* __restrict__ WT, int K, int N) {
  __shared__ float Ts[64][65];
  const int tid = threadIdx.x;
  const int n0 = blockIdx.x * 64, k0 = blockIdx.y * 64;
#pragma unroll
  for (int p = 0; p < 4; ++p) {
    int r = p * 16 + (tid >> 4), c = (tid & 15) * 4;
    float4 v = *(const float4*)(W + (size_t)(k0 + r) * N + n0 + c);
    Ts[r][c] = v.x; Ts[r][c + 1] = v.y; Ts[r][c + 2] = v.z; Ts[r][c + 3] = v.w;
  }
  __syncthreads();
#pragma unroll
  for (int p = 0; p < 4; ++p) {
    int n = p * 16 + (tid >> 4), kq = (tid & 15) * 4;
    u16x4 o;
    o[0] = f2b(Ts[kq + 0][n]); o[1] = f2b(Ts[kq + 1][n]);
    o[2] = f2b(Ts[kq + 2][n]); o[3] = f2b(Ts[kq + 3][n]);
    *(u16x4*)(WT + (size_t)(n0 + n) * K + k0 + kq) = o;
  }
}

// ---------------------------------------------------------------------------
// V [B*KV][S][HD] bf16 -> Vt [B*KV][HD][S] bf16 (tiled 64x64)
// ---------------------------------------------------------------------------
__global__ __launch_bounds__(256) void transpose_v(const u16* __restrict__ V,
                                                   u16* __restrict__ Vt) {
  __shared__ u16 Ts[64][72];
  const int tid = threadIdx.x;
  const int s0 = blockIdx.x * 64, d0 = blockIdx.y * 64, hb = blockIdx.z;
  const u16* src = V + ((size_t)hb * S_ + s0) * HD_ + d0;
#pragma unroll
  for (int p = 0; p < 2; ++p) {
    int r = p * 32 + (tid >> 3), seg = (tid & 7) * 8;
    u16x8 v = *(const u16x8*)(src + (size_t)r * HD_ + seg);
#pragma unroll
    for (int j = 0; j < 8; ++j) Ts[r][seg + j] = v[j];
  }
  __syncthreads();
  u16* dst = Vt + ((size_t)hb * HD_ + d0) * S_ + s0;
#pragma unroll
  for (int p = 0; p < 2; ++p) {
    int d = p * 32 + (tid >> 3), seg = (tid & 7) * 8;
    u16x8 o;
#pragma unroll
    for (int j = 0; j < 8; ++j) o[j] = Ts[seg + j][d];
    *(u16x8*)(dst + (size_t)d * S_ + seg) = o;
  }
}

// ---------------------------------------------------------------------------
// RoPE in-place on bf16 head-major [BH][S][HD], with output scale folded in.
// ---------------------------------------------------------------------------
__global__ __launch_bounds__(256) void rope_bf16(unsigned* __restrict__ T,
                                                 const float* __restrict__ cs,
                                                 const float* __restrict__ sn,
                                                 int total, float scale) {
  int idx = blockIdx.x * 256 + threadIdx.x;
  if (idx >= total) return;
  int i = idx & 63, s = (idx >> 6) & (S_ - 1);
  float c = cs[s * 64 + i], si = sn[s * 64 + i];
  unsigned v = T[idx];
  float re = b2f((u16)(v & 0xffffu)), im = b2f((u16)(v >> 16));
  float ore = (re * c - im * si) * scale, oim = (re * si + im * c) * scale;
  T[idx] = (unsigned)f2b(ore) | ((unsigned)f2b(oim) << 16);
}

// ---------------------------------------------------------------------------
// bf16 MFMA GEMM, m97 structure (kept for the small K/V projections, N=1024).
// ---------------------------------------------------------------------------
template <int OUT_MODE>
__global__ __launch_bounds__(256) void gemm_bf16(
    const u16* __restrict__ A, const u16* __restrict__ Bt,
    void* __restrict__ Cout, int M, int N, int K, int heads) {
  __shared__ u16 As[128 * 64];
  __shared__ u16 Bs[128 * 64];
  const int tid = threadIdx.x, lane = tid & 63;
  const int wbase = tid & ~63;
  const int row0 = blockIdx.y * 128, col0 = blockIdx.x * 128;
  const int wm = ((tid >> 6) >> 1) * 64, wn = ((tid >> 6) & 1) * 64;

  f32x4 acc[4][4];
#pragma unroll
  for (int i = 0; i < 4; ++i)
#pragma unroll
    for (int j = 0; j < 4; ++j) acc[i][j] = (f32x4){0.f, 0.f, 0.f, 0.f};

  const int nk = K >> 6;
  for (int kt = 0; kt < nk; ++kt) {
    const int k0 = kt << 6;
#pragma unroll
    for (int i = 0; i < 4; ++i) {
      int g = i * 256 + tid;
      int r = g >> 3, ss = (g & 7) ^ (r & 7);
      async_copy16(A + (size_t)(row0 + r) * K + k0 + ss * 8,
                   (char*)As + (i * 256 + wbase) * 16);
    }
#pragma unroll
    for (int i = 0; i < 4; ++i) {
      int g = i * 256 + tid;
      int r = g >> 3, ss = (g & 7) ^ (r & 7);
      async_copy16(Bt + (size_t)(col0 + r) * K + k0 + ss * 8,
                   (char*)Bs + (i * 256 + wbase) * 16);
    }
    __syncthreads();
#pragma unroll
    for (int ks = 0; ks < 2; ++ks) {
      bf16x8 af[4], bf[4];
#pragma unroll
      for (int mi = 0; mi < 4; ++mi) {
        int r = wm + mi * 16 + (lane & 15);
        int off = (ks * 64 + ((lane >> 4) << 4)) ^ ((r & 7) << 4);
        af[mi] = *(const bf16x8*)((const char*)As + r * 128 + off);
      }
#pragma unroll
      for (int ni = 0; ni < 4; ++ni) {
        int r = wn + ni * 16 + (lane & 15);
        int off = (ks * 64 + ((lane >> 4) << 4)) ^ ((r & 7) << 4);
        bf[ni] = *(const bf16x8*)((const char*)Bs + r * 128 + off);
      }
#pragma unroll
      for (int mi = 0; mi < 4; ++mi)
#pragma unroll
        for (int ni = 0; ni < 4; ++ni)
          acc[mi][ni] = __builtin_amdgcn_mfma_f32_16x16x32_bf16(
              af[mi], bf[ni], acc[mi][ni], 0, 0, 0);
    }
    __syncthreads();
  }

#pragma unroll
  for (int mi = 0; mi < 4; ++mi)
#pragma unroll
    for (int ni = 0; ni < 4; ++ni) {
      int mb = row0 + wm + mi * 16 + ((lane >> 4) << 2);
      int n = col0 + wn + ni * 16 + (lane & 15);
#pragma unroll
      for (int r = 0; r < 4; ++r) {
        int m = mb + r;
        float v = acc[mi][ni][r];
        if (OUT_MODE == 0) {
          ((float*)Cout)[(size_t)m * N + n] = v;
        } else {
          int b = m >> 11, s = m & (S_ - 1);
          int h = n >> 7, d = n & (HD_ - 1);
          ((u16*)Cout)[(((size_t)(b * heads + h)) * S_ + s) * HD_ + d] = f2b(v);
        }
      }
    }
}

// ---------------------------------------------------------------------------
// 256x256 8-phase bf16 MFMA GEMM (T2+T3+T4+T5). C = A[M][K] @ Bt[N][K]^T.
// 512 thr / 8 waves (2m x 4n), wave tile 128x64, BK=64 split into 2 K-halves.
// LDS: per operand a ring of 4 half-slots (256 rows x 32 k = 16 KiB each);
// total 128 KiB. Slot for (tile tau, ks) = (2*tau+ks)&3.
// Per phase: {4-8 ds_read_b128; stage 1 half (2 global_load_lds); s_barrier;
// setprio(1); 16 MFMA; setprio(0); [phase3: vmcnt(4) counted]; s_barrier}.
// Staging leads compute by 6 halves; vmcnt never drained to 0 in steady state.
// Within-slot swizzle: byte = (row>>1)*128+(row&1)*64+((g^((row>>1)&3))<<4)
// -> 2 lanes/16B-slot per quarter-wave on ds_read_b128 (conflict-free), with
// the inverse permutation applied to the global source (linear LDS dest).
// ---------------------------------------------------------------------------
template <int OUT_MODE>
__global__ __launch_bounds__(512) void gemm256(
    const u16* __restrict__ A, const u16* __restrict__ Bt,
    void* __restrict__ Cout, int M, int N, int K, int heads) {
  __shared__ u16 lds[65536];  // A: bytes [0,65536), B: [65536,131072)
  char* const ldsb = (char*)lds;
  const int tid = threadIdx.x, lane = tid & 63, wid = tid >> 6;
  const int q = lane & 15, g = lane >> 4;
  const int wm = wid >> 2, wn = wid & 3;
  const int row0 = blockIdx.y * 256, col0 = blockIdx.x * 256;
  const int nk = K >> 6, nh = nk << 2;

  // Staging source (inverse-swizzled): lds granule j=u*512+tid holds
  // row=(j>>3)*2+((j>>2)&1), k-granule colg=(j&3)^((j>>3)&3) of the half.
  const u16* srcA[2];
  const u16* srcB[2];
#pragma unroll
  for (int u = 0; u < 2; ++u) {
    int j = u * 512 + tid;
    int row = ((j >> 3) << 1) + ((j >> 2) & 1);
    int colg = (j & 3) ^ ((j >> 3) & 3);
    srcA[u] = A + (size_t)(row0 + row) * K + colg * 8;
    srcB[u] = Bt + (size_t)(col0 + row) * K + colg * 8;
  }

  auto STAGE = [&](int h) {
    if (h >= nh) return;
    int tau = h >> 2, ks = (h >> 1) & 1, op = h & 1;
    int slot = (2 * tau + ks) & 3;
    int koff = tau * 64 + ks * 32;
    char* lbase = ldsb + op * 65536 + slot * 16384 + wid * 1024;
#pragma unroll
    for (int u = 0; u < 2; ++u)
      async_copy16((op ? srcB[u] : srcA[u]) + koff, lbase + u * 8192);
  };

  // Per-thread slot-relative ds_read byte offsets for fragments.
  int aread[8], bread[4];
#pragma unroll
  for (int mi = 0; mi < 8; ++mi) {
    int row = wm * 128 + mi * 16 + q;
    aread[mi] = (row >> 1) * 128 + (row & 1) * 64 + ((g ^ ((row >> 1) & 3)) << 4);
  }
#pragma unroll
  for (int ni = 0; ni < 4; ++ni) {
    int row = wn * 64 + ni * 16 + q;
    bread[ni] = (row >> 1) * 128 + (row & 1) * 64 + ((g ^ ((row >> 1) & 3)) << 4);
  }

  f32x4 acc[8][4];
#pragma unroll
  for (int i = 0; i < 8; ++i)
#pragma unroll
    for (int j = 0; j < 4; ++j) acc[i][j] = (f32x4){0.f, 0.f, 0.f, 0.f};

  // Prologue: stage halves 0..5 (tile0 + tile1's ks0), wait tile0, barrier.
#pragma unroll
  for (int h = 0; h < 6; ++h) STAGE(h);
  asm volatile("s_waitcnt vmcnt(4)" ::: "memory");
  bar();

  for (int t = 0; t < nk; ++t) {
    const int s0 = (2 * t) & 3, s1 = (2 * t + 1) & 3;
    const char* As0 = ldsb + s0 * 16384;
    const char* Bs0 = ldsb + 65536 + s0 * 16384;
    const char* As1 = ldsb + s1 * 16384;
    const char* Bs1 = ldsb + 65536 + s1 * 16384;
    bf16x8 af[4], bfr[4];

    // ===== phase 0: quad (m0-3, ks0)
#pragma unroll
    for (int i = 0; i < 4; ++i) af[i] = *(const bf16x8*)(As0 + aread[i]);
#pragma unroll
    for (int i = 0; i < 4; ++i) bfr[i] = *(const bf16x8*)(Bs0 + bread[i]);
    STAGE(4 * t + 6);
    bar();
    __builtin_amdgcn_s_setprio(1);
#pragma unroll
    for (int mi = 0; mi < 4; ++mi)
#pragma unroll
      for (int ni = 0; ni < 4; ++ni)
        acc[mi][ni] = __builtin_amdgcn_mfma_f32_16x16x32_bf16(
            af[mi], bfr[ni], acc[mi][ni], 0, 0, 0);
    __builtin_amdgcn_s_setprio(0);
    bar();

    // ===== phase 1: quad (m4-7, ks0)  (B ks0 reused)
#pragma unroll
    for (int i = 0; i < 4; ++i) af[i] = *(const bf16x8*)(As0 + aread[4 + i]);
    STAGE(4 * t + 7);
    bar();
    __builtin_amdgcn_s_setprio(1);
#pragma unroll
    for (int mi = 0; mi < 4; ++mi)
#pragma unroll
      for (int ni = 0; ni < 4; ++ni)
        acc[4 + mi][ni] = __builtin_amdgcn_mfma_f32_16x16x32_bf16(
            af[mi], bfr[ni], acc[4 + mi][ni], 0, 0, 0);
    __builtin_amdgcn_s_setprio(0);
    bar();

    // ===== phase 2: quad (m0-3, ks1)
#pragma unroll
    for (int i = 0; i < 4; ++i) af[i] = *(const bf16x8*)(As1 + aread[i]);
#pragma unroll
    for (int i = 0; i < 4; ++i) bfr[i] = *(const bf16x8*)(Bs1 + bread[i]);
    STAGE(4 * t + 8);
    bar();
    __builtin_amdgcn_s_setprio(1);
#pragma unroll
    for (int mi = 0; mi < 4; ++mi)
#pragma unroll
      for (int ni = 0; ni < 4; ++ni)
        acc[mi][ni] = __builtin_amdgcn_mfma_f32_16x16x32_bf16(
            af[mi], bfr[ni], acc[mi][ni], 0, 0, 0);
    __builtin_amdgcn_s_setprio(0);
    bar();

    // ===== phase 3: quad (m4-7, ks1) + per-tile counted vmcnt
#pragma unroll
    for (int i = 0; i < 4; ++i) af[i] = *(const bf16x8*)(As1 + aread[4 + i]);
    STAGE(4 * t + 9);
    bar();
    __builtin_amdgcn_s_setprio(1);
#pragma unroll
    for (int mi = 0; mi < 4; ++mi)
#pragma unroll
      for (int ni = 0; ni < 4; ++ni)
        acc[4 + mi][ni] = __builtin_amdgcn_mfma_f32_16x16x32_bf16(
            af[mi], bfr[ni], acc[4 + mi][ni], 0, 0, 0);
    __builtin_amdgcn_s_setprio(0);
    if (t < nk - 2)
      asm volatile("s_waitcnt vmcnt(4)" ::: "memory");  // next tile landed
    else if (t == nk - 2)
      asm volatile("s_waitcnt vmcnt(0)" ::: "memory");  // final drain
    bar();
  }

  // Epilogue: D layout col=lane&15 (n), row=(lane>>4)*4+r (m).
#pragma unroll
  for (int mi = 0; mi < 8; ++mi)
#pragma unroll
    for (int ni = 0; ni < 4; ++ni) {
      int mb = row0 + wm * 128 + mi * 16 + (g << 2);
      int n = col0 + wn * 64 + ni * 16 + q;
#pragma unroll
      for (int r = 0; r < 4; ++r) {
        int m = mb + r;
        float v = acc[mi][ni][r];
        if (OUT_MODE == 0) {
          ((float*)Cout)[(size_t)m * N + n] = v;
        } else {
          int b = m >> 11, s = m & (S_ - 1);
          int h = n >> 7, d = n & (HD_ - 1);
          ((u16*)Cout)[(((size_t)(b * heads + h)) * S_ + s) * HD_ + d] = f2b(v);
        }
      }
    }
}

// ---------------------------------------------------------------------------
// Flash attention (unchanged from R4 — verified).
// ---------------------------------------------------------------------------
__global__ __launch_bounds__(256) void attn_mfma(
    const u16* __restrict__ Qb, const u16* __restrict__ Kb,
    const u16* __restrict__ Vt, u16* __restrict__ AO) {
  __shared__ u16 Ks[64 * 128];
  __shared__ u16 Vs[128 * 64];
  __shared__ u16 Ps[4][16 * 64];

  const int tid = threadIdx.x, lane = tid & 63, wid = tid >> 6;
  const int wbase = tid & ~63;
  const int pid = blockIdx.x, h = blockIdx.y, b = blockIdx.z;
  const int kvh = h >> 2;
  const int qq = lane & 15, g = lane >> 4;

  const u16* Kbase = Kb + ((size_t)(b * KV_ + kvh) * S_) * HD_;
  const u16* Vbase = Vt + ((size_t)(b * KV_ + kvh) * HD_) * S_;

  const u16* Kl[4];
  const u16* Vl[4];
#pragma unroll
  for (int i = 0; i < 4; ++i) {
    int gg = i * 256 + tid;
    int rK = gg >> 4, ssK = (gg & 15) ^ (rK & 7);
    Kl[i] = Kbase + (size_t)rK * HD_ + ssK * 8;
    int rV = gg >> 3, ssV = (gg & 7) ^ (rV & 7);
    Vl[i] = Vbase + (size_t)rV * S_ + ssV * 8;
  }
  char* const pw = (char*)Ps[wid];

  for (int half = 0; half < 2; ++half) {
    const int qt = half ? (31 - pid) : pid;
    const int q0 = qt * 64;

    bf16x8 qf[4];
    {
      const u16* qrow = Qb + ((size_t)(b * H_ + h) * S_ + q0 + wid * 16 + qq) * HD_ +
                        (g << 3);
#pragma unroll
      for (int ks = 0; ks < 4; ++ks) qf[ks] = *(const bf16x8*)(qrow + ks * 32);
    }

    f32x4 oacc[8];
#pragma unroll
    for (int i = 0; i < 8; ++i) oacc[i] = (f32x4){0.f, 0.f, 0.f, 0.f};
    float mrow = -3e38f, lrow = 0.f;

    for (int kt = 0; kt <= qt; ++kt) {
      const int kv0 = kt * 64;
#pragma unroll
      for (int i = 0; i < 4; ++i)
        async_copy16(Kl[i] + (size_t)kv0 * HD_, (char*)Ks + (i * 256 + wbase) * 16);
#pragma unroll
      for (int i = 0; i < 4; ++i)
        async_copy16(Vl[i] + kv0, (char*)Vs + (i * 256 + wbase) * 16);
      __syncthreads();

      f32x4 sacc[4];
#pragma unroll
      for (int nf = 0; nf < 4; ++nf) sacc[nf] = (f32x4){0.f, 0.f, 0.f, 0.f};
#pragma unroll
      for (int nf = 0; nf < 4; ++nf) {
        int r = nf * 16 + qq;
        const char* base = (const char*)Ks + r * 256;
#pragma unroll
        for (int ks = 0; ks < 4; ++ks) {
          int off = (ks * 64 + (g << 4)) ^ ((r & 7) << 4);
          bf16x8 kf = *(const bf16x8*)(base + off);
          sacc[nf] =
              __builtin_amdgcn_mfma_f32_16x16x32_bf16(kf, qf[ks], sacc[nf], 0, 0, 0);
        }
      }

      float rmax = -3e38f;
      if (kt == qt) {
        const int qg = q0 + wid * 16 + qq;
#pragma unroll
        for (int nf = 0; nf < 4; ++nf)
#pragma unroll
          for (int r = 0; r < 4; ++r) {
            int kg = kv0 + nf * 16 + g * 4 + r;
            float sv = (kg > qg) ? -3e38f : sacc[nf][r];
            sacc[nf][r] = sv;
            rmax = fmaxf(rmax, sv);
          }
      } else {
#pragma unroll
        for (int nf = 0; nf < 4; ++nf)
#pragma unroll
          for (int r = 0; r < 4; ++r) rmax = fmaxf(rmax, sacc[nf][r]);
      }
      rmax = fmaxf(rmax, __shfl_xor(rmax, 16, 64));
      rmax = fmaxf(rmax, __shfl_xor(rmax, 32, 64));
      const float mnew = fmaxf(mrow, rmax);
      const float fsc = exp2f(mrow - mnew);
      mrow = mnew;
      float psum = 0.f;
#pragma unroll
      for (int nf = 0; nf < 4; ++nf)
#pragma unroll
        for (int r = 0; r < 4; ++r) {
          float p = exp2f(sacc[nf][r] - mnew);
          sacc[nf][r] = p;
          psum += p;
        }
      psum += __shfl_xor(psum, 16, 64);
      psum += __shfl_xor(psum, 32, 64);
      lrow = lrow * fsc + psum;

      const float fr0 = __shfl(fsc, g * 4 + 0);
      const float fr1 = __shfl(fsc, g * 4 + 1);
      const float fr2 = __shfl(fsc, g * 4 + 2);
      const float fr3 = __shfl(fsc, g * 4 + 3);
#pragma unroll
      for (int df = 0; df < 8; ++df) {
        oacc[df][0] *= fr0; oacc[df][1] *= fr1;
        oacc[df][2] *= fr2; oacc[df][3] *= fr3;
      }

#pragma unroll
      for (int nf = 0; nf < 4; ++nf) {
        u16x4 pk;
#pragma unroll
        for (int r = 0; r < 4; ++r) pk[r] = f2b(sacc[nf][r]);
        int gran = (nf * 2 + (g >> 1)) ^ (qq & 7);
        *(u16x4*)(pw + qq * 128 + gran * 16 + (g & 1) * 8) = pk;
      }

#pragma unroll
      for (int ks = 0; ks < 2; ++ks) {
        int poff = qq * 128 + ((ks * 64 + (g << 4)) ^ ((qq & 7) << 4));
        bf16x8 pf = *(const bf16x8*)(pw + poff);
#pragma unroll
        for (int df = 0; df < 8; ++df) {
          int vr = df * 16 + qq;
          int voff = (ks * 64 + (g << 4)) ^ ((vr & 7) << 4);
          bf16x8 vf = *(const bf16x8*)((const char*)Vs + vr * 128 + voff);
          oacc[df] =
              __builtin_amdgcn_mfma_f32_16x16x32_bf16(pf, vf, oacc[df], 0, 0, 0);
        }
      }
      __syncthreads();
    }

    const float linv = 1.f / lrow;
    const float i0 = __shfl(linv, g * 4 + 0);
    const float i1 = __shfl(linv, g * 4 + 1);
    const float i2 = __shfl(linv, g * 4 + 2);
    const float i3 = __shfl(linv, g * 4 + 3);
    const float inv[4] = {i0, i1, i2, i3};
#pragma unroll
    for (int df = 0; df < 8; ++df)
#pragma unroll
      for (int r = 0; r < 4; ++r) {
        int sq = q0 + wid * 16 + g * 4 + r;
        AO[(size_t)(b * S_ + sq) * (H_ * HD_) + h * HD_ + df * 16 + qq] =
            f2b(oacc[df][r] * inv[r]);
      }
  }
}

// ---------------------------------------------------------------------------
extern "C" void kernel_launch(void* const* d_in, const int* in_sizes, int n_in,
                              void* d_out, int out_size, void* d_ws, size_t ws_size,
                              hipStream_t stream) {
  const float* x  = (const float*)d_in[0];
  const float* wq = (const float*)d_in[1];
  const float* wk = (const float*)d_in[2];
  const float* wv = (const float*)d_in[3];
  const float* wo = (const float*)d_in[4];
  const float* fc = (const float*)d_in[5];
  const float* fs = (const float*)d_in[6];
  float* out = (float*)d_out;

  // Workspace (u16 elements), 160 MiB total — same layout as R3/R4.
  u16* ws  = (u16*)d_ws;
  u16* wqT = ws;
  u16* VtB = ws;              // alias of wqT region (after wqT last use)
  u16* xb  = ws + 16777216;
  u16* AOb = xb;              // alias of xb region (after xb last use)
  u16* woT = ws + 33554432;
  u16* Qh  = ws + 50331648;
  u16* wkT = ws + 67108864;
  u16* wvT = ws + 71303168;
  u16* Kh  = ws + 75497472;
  u16* Vh  = ws + 79691776;

  dim3 blk(256);

  cvt_bf16<<<dim3(16384), blk, 0, stream>>>(x, xb, 4194304);
  transpose_cvt<<<dim3(64, 64), blk, 0, stream>>>(wq, wqT, DIM_, H_ * HD_);
  transpose_cvt<<<dim3(16, 64), blk, 0, stream>>>(wk, wkT, DIM_, KV_ * HD_);
  transpose_cvt<<<dim3(16, 64), blk, 0, stream>>>(wv, wvT, DIM_, KV_ * HD_);
  transpose_cvt<<<dim3(64, 64), blk, 0, stream>>>(wo, woT, H_ * HD_, DIM_);

  gemm256<1><<<dim3(16, 16), dim3(512), 0, stream>>>(xb, wqT, Qh, 4096, 4096, 4096, H_);
  gemm_bf16<1><<<dim3(8, 32), blk, 0, stream>>>(xb, wkT, Kh, 4096, 1024, 4096, KV_);
  gemm_bf16<1><<<dim3(8, 32), blk, 0, stream>>>(xb, wvT, Vh, 4096, 1024, 4096, KV_);

  rope_bf16<<<dim3(32768), blk, 0, stream>>>((unsigned*)Qh, fc, fs, 8388608, QSCALE_);
  rope_bf16<<<dim3(8192), blk, 0, stream>>>((unsigned*)Kh, fc, fs, 2097152, 1.0f);

  transpose_v<<<dim3(32, 2, 16), blk, 0, stream>>>(Vh, VtB);

  attn_mfma<<<dim3(16, 32, 2), blk, 0, stream>>>(Qh, Kh, VtB, AOb);

  gemm256<0><<<dim3(16, 16), dim3(512), 0, stream>>>(AOb, woT, out, 4096, 4096, 4096, 0);
}

// Round 7
// 557.423 us; speedup vs baseline: 17.5483x; 1.1952x over previous
//
#include <hip/hip_runtime.h>
#include <math.h>

#define B_ 2
#define S_ 2048
#define DIM_ 4096
#define H_ 32
#define KV_ 8
#define HD_ 128
#define SCALE_ 0.08838834764831844f   // 128^-0.5
#define QSCALE_ 0.12751744154254998f  // SCALE_ * log2(e)
#define KVOFF_ 4194304                // B*KV*S*HD elements (K->V group stride)

typedef unsigned short u16;
typedef __attribute__((ext_vector_type(8))) short bf16x8;
typedef __attribute__((ext_vector_type(4))) float f32x4;
typedef __attribute__((ext_vector_type(8))) unsigned short u16x8;
typedef __attribute__((ext_vector_type(4))) unsigned short u16x4;

__device__ __forceinline__ u16 f2b(float f) {  // RNE f32->bf16
  union { float f; unsigned u; } v; v.f = f;
  unsigned r = v.u + 0x7fffu + ((v.u >> 16) & 1u);
  return (u16)(r >> 16);
}
__device__ __forceinline__ float b2f(u16 h) {
  union { unsigned u; float f; } v; v.u = ((unsigned)h) << 16;
  return v.f;
}
// HW packed f32->bf16 (RNE): lo -> bits[15:0], hi -> bits[31:16]
__device__ __forceinline__ unsigned cvt_pk_bf16(float lo, float hi) {
  unsigned r;
  asm("v_cvt_pk_bf16_f32 %0, %1, %2" : "=v"(r) : "v"(lo), "v"(hi));
  return r;
}
// Direct-to-LDS async copy, 16B/lane. LDS dest = wave-uniform base + lane*16.
__device__ __forceinline__ void async_copy16(const void* g, void* l) {
  __builtin_amdgcn_global_load_lds(
      (const __attribute__((address_space(1))) void*)g,
      (__attribute__((address_space(3))) void*)l, 16, 0, 0);
}
// Raw barrier WITH compiler memory fence (no vmcnt drain, unlike __syncthreads)
__device__ __forceinline__ void bar() {
  asm volatile("s_barrier" ::: "memory");
}

// ---------------------------------------------------------------------------
// fp32 -> bf16 bulk convert (vectorized)
// ---------------------------------------------------------------------------
__global__ __launch_bounds__(256) void cvt_bf16(const float* __restrict__ in,
                                                u16* __restrict__ out, int n4) {
  int i = blockIdx.x * 256 + threadIdx.x;
  if (i >= n4) return;
  float4 v = ((const float4*)in)[i];
  u16x4 o; o[0] = f2b(v.x); o[1] = f2b(v.y); o[2] = f2b(v.z); o[3] = f2b(v.w);
  ((u16x4*)out)[i] = o;
}

// ---------------------------------------------------------------------------
// W[K][N] fp32 -> WT[N][K] bf16  (tiled 64x64 via LDS)
// ---------------------------------------------------------------------------
__global__ __launch_bounds__(256) void transpose_cvt(
    const float* __restrict__ W, u16* __restrict__ WT, int K, int N) {
  __shared__ float Ts[64][65];
  const int tid = threadIdx.x;
  const int n0 = blockIdx.x * 64, k0 = blockIdx.y * 64;
#pragma unroll
  for (int p = 0; p < 4; ++p) {
    int r = p * 16 + (tid >> 4), c = (tid & 15) * 4;
    float4 v = *(const float4*)(W + (size_t)(k0 + r) * N + n0 + c);
    Ts[r][c] = v.x; Ts[r][c + 1] = v.y; Ts[r][c + 2] = v.z; Ts[r][c + 3] = v.w;
  }
  __syncthreads();
#pragma unroll
  for (int p = 0; p < 4; ++p) {
    int n = p * 16 + (tid >> 4), kq = (tid & 15) * 4;
    u16x4 o;
    o[0] = f2b(Ts[kq + 0][n]); o[1] = f2b(Ts[kq + 1][n]);
    o[2] = f2b(Ts[kq + 2][n]); o[3] = f2b(Ts[kq + 3][n]);
    *(u16x4*)(WT + (size_t)(n0 + n) * K + k0 + kq) = o;
  }
}

// ---------------------------------------------------------------------------
// V [B*KV][S][HD] bf16 -> Vt [B*KV][HD][S] bf16 (tiled 64x64)
// ---------------------------------------------------------------------------
__global__ __launch_bounds__(256) void transpose_v(const u16* __restrict__ V,
                                                   u16* __restrict__ Vt) {
  __shared__ u16 Ts[64][72];
  const int tid = threadIdx.x;
  const int s0 = blockIdx.x * 64, d0 = blockIdx.y * 64, hb = blockIdx.z;
  const u16* src = V + ((size_t)hb * S_ + s0) * HD_ + d0;
#pragma unroll
  for (int p = 0; p < 2; ++p) {
    int r = p * 32 + (tid >> 3), seg = (tid & 7) * 8;
    u16x8 v = *(const u16x8*)(src + (size_t)r * HD_ + seg);
#pragma unroll
    for (int j = 0; j < 8; ++j) Ts[r][seg + j] = v[j];
  }
  __syncthreads();
  u16* dst = Vt + ((size_t)hb * HD_ + d0) * S_ + s0;
#pragma unroll
  for (int p = 0; p < 2; ++p) {
    int d = p * 32 + (tid >> 3), seg = (tid & 7) * 8;
    u16x8 o;
#pragma unroll
    for (int j = 0; j < 8; ++j) o[j] = Ts[seg + j][d];
    *(u16x8*)(dst + (size_t)d * S_ + seg) = o;
  }
}

// ---------------------------------------------------------------------------
// RoPE in-place on bf16 head-major [BH][S][HD] (used for K only now).
// ---------------------------------------------------------------------------
__global__ __launch_bounds__(256) void rope_bf16(unsigned* __restrict__ T,
                                                 const float* __restrict__ cs,
                                                 const float* __restrict__ sn,
                                                 int total, float scale) {
  int idx = blockIdx.x * 256 + threadIdx.x;
  if (idx >= total) return;
  int i = idx & 63, s = (idx >> 6) & (S_ - 1);
  float c = cs[s * 64 + i], si = sn[s * 64 + i];
  unsigned v = T[idx];
  float re = b2f((u16)(v & 0xffffu)), im = b2f((u16)(v >> 16));
  float ore = (re * c - im * si) * scale, oim = (re * si + im * c) * scale;
  T[idx] = (unsigned)f2b(ore) | ((unsigned)f2b(oim) << 16);
}

// ---------------------------------------------------------------------------
// bf16 MFMA GEMM, m97 structure.
// OUT_MODE 0: fp32 row-major. OUT_MODE 1: bf16 head-major.
// OUT_MODE 2: combined K|V projection (N=2048): heads 0-7 -> K group,
//             heads 8-15 -> V group at +KVOFF_ elements.
// ---------------------------------------------------------------------------
template <int OUT_MODE>
__global__ __launch_bounds__(256) void gemm_bf16(
    const u16* __restrict__ A, const u16* __restrict__ Bt,
    void* __restrict__ Cout, int M, int N, int K, int heads) {
  __shared__ u16 As[128 * 64];
  __shared__ u16 Bs[128 * 64];
  const int tid = threadIdx.x, lane = tid & 63;
  const int wbase = tid & ~63;
  const int row0 = blockIdx.y * 128, col0 = blockIdx.x * 128;
  const int wm = ((tid >> 6) >> 1) * 64, wn = ((tid >> 6) & 1) * 64;

  f32x4 acc[4][4];
#pragma unroll
  for (int i = 0; i < 4; ++i)
#pragma unroll
    for (int j = 0; j < 4; ++j) acc[i][j] = (f32x4){0.f, 0.f, 0.f, 0.f};

  const int nk = K >> 6;
  for (int kt = 0; kt < nk; ++kt) {
    const int k0 = kt << 6;
#pragma unroll
    for (int i = 0; i < 4; ++i) {
      int g = i * 256 + tid;
      int r = g >> 3, ss = (g & 7) ^ (r & 7);
      async_copy16(A + (size_t)(row0 + r) * K + k0 + ss * 8,
                   (char*)As + (i * 256 + wbase) * 16);
    }
#pragma unroll
    for (int i = 0; i < 4; ++i) {
      int g = i * 256 + tid;
      int r = g >> 3, ss = (g & 7) ^ (r & 7);
      async_copy16(Bt + (size_t)(col0 + r) * K + k0 + ss * 8,
                   (char*)Bs + (i * 256 + wbase) * 16);
    }
    __syncthreads();
#pragma unroll
    for (int ks = 0; ks < 2; ++ks) {
      bf16x8 af[4], bf[4];
#pragma unroll
      for (int mi = 0; mi < 4; ++mi) {
        int r = wm + mi * 16 + (lane & 15);
        int off = (ks * 64 + ((lane >> 4) << 4)) ^ ((r & 7) << 4);
        af[mi] = *(const bf16x8*)((const char*)As + r * 128 + off);
      }
#pragma unroll
      for (int ni = 0; ni < 4; ++ni) {
        int r = wn + ni * 16 + (lane & 15);
        int off = (ks * 64 + ((lane >> 4) << 4)) ^ ((r & 7) << 4);
        bf[ni] = *(const bf16x8*)((const char*)Bs + r * 128 + off);
      }
#pragma unroll
      for (int mi = 0; mi < 4; ++mi)
#pragma unroll
        for (int ni = 0; ni < 4; ++ni)
          acc[mi][ni] = __builtin_amdgcn_mfma_f32_16x16x32_bf16(
              af[mi], bf[ni], acc[mi][ni], 0, 0, 0);
    }
    __syncthreads();
  }

#pragma unroll
  for (int mi = 0; mi < 4; ++mi)
#pragma unroll
    for (int ni = 0; ni < 4; ++ni) {
      int mb = row0 + wm + mi * 16 + ((lane >> 4) << 2);
      int n = col0 + wn + ni * 16 + (lane & 15);
#pragma unroll
      for (int r = 0; r < 4; ++r) {
        int m = mb + r;
        float v = acc[mi][ni][r];
        if (OUT_MODE == 0) {
          ((float*)Cout)[(size_t)m * N + n] = v;
        } else if (OUT_MODE == 1) {
          int b = m >> 11, s = m & (S_ - 1);
          int h = n >> 7, d = n & (HD_ - 1);
          ((u16*)Cout)[(((size_t)(b * heads + h)) * S_ + s) * HD_ + d] = f2b(v);
        } else {  // combined K|V
          int b = m >> 11, s = m & (S_ - 1);
          int hh = n >> 7, d = n & (HD_ - 1);
          size_t base = (size_t)(hh >> 3) * KVOFF_;
          ((u16*)Cout)[base + (((size_t)(b * 8 + (hh & 7))) * S_ + s) * HD_ + d] =
              f2b(v);
        }
      }
    }
}

// ---------------------------------------------------------------------------
// 256x256 8-phase bf16 MFMA GEMM (unchanged from R6 — verified).
// ---------------------------------------------------------------------------
template <int OUT_MODE>
__global__ __launch_bounds__(512) void gemm256(
    const u16* __restrict__ A, const u16* __restrict__ Bt,
    void* __restrict__ Cout, int M, int N, int K, int heads) {
  __shared__ u16 lds[65536];  // A: bytes [0,65536), B: [65536,131072)
  char* const ldsb = (char*)lds;
  const int tid = threadIdx.x, lane = tid & 63, wid = tid >> 6;
  const int q = lane & 15, g = lane >> 4;
  const int wm = wid >> 2, wn = wid & 3;
  const int row0 = blockIdx.y * 256, col0 = blockIdx.x * 256;
  const int nk = K >> 6, nh = nk << 2;

  const u16* srcA[2];
  const u16* srcB[2];
#pragma unroll
  for (int u = 0; u < 2; ++u) {
    int j = u * 512 + tid;
    int row = ((j >> 3) << 1) + ((j >> 2) & 1);
    int colg = (j & 3) ^ ((j >> 3) & 3);
    srcA[u] = A + (size_t)(row0 + row) * K + colg * 8;
    srcB[u] = Bt + (size_t)(col0 + row) * K + colg * 8;
  }

  auto STAGE = [&](int h) {
    if (h >= nh) return;
    int tau = h >> 2, ks = (h >> 1) & 1, op = h & 1;
    int slot = (2 * tau + ks) & 3;
    int koff = tau * 64 + ks * 32;
    char* lbase = ldsb + op * 65536 + slot * 16384 + wid * 1024;
#pragma unroll
    for (int u = 0; u < 2; ++u)
      async_copy16((op ? srcB[u] : srcA[u]) + koff, lbase + u * 8192);
  };

  int aread[8], bread[4];
#pragma unroll
  for (int mi = 0; mi < 8; ++mi) {
    int row = wm * 128 + mi * 16 + q;
    aread[mi] = (row >> 1) * 128 + (row & 1) * 64 + ((g ^ ((row >> 1) & 3)) << 4);
  }
#pragma unroll
  for (int ni = 0; ni < 4; ++ni) {
    int row = wn * 64 + ni * 16 + q;
    bread[ni] = (row >> 1) * 128 + (row & 1) * 64 + ((g ^ ((row >> 1) & 3)) << 4);
  }

  f32x4 acc[8][4];
#pragma unroll
  for (int i = 0; i < 8; ++i)
#pragma unroll
    for (int j = 0; j < 4; ++j) acc[i][j] = (f32x4){0.f, 0.f, 0.f, 0.f};

#pragma unroll
  for (int h = 0; h < 6; ++h) STAGE(h);
  asm volatile("s_waitcnt vmcnt(4)" ::: "memory");
  bar();

  for (int t = 0; t < nk; ++t) {
    const int s0 = (2 * t) & 3, s1 = (2 * t + 1) & 3;
    const char* As0 = ldsb + s0 * 16384;
    const char* Bs0 = ldsb + 65536 + s0 * 16384;
    const char* As1 = ldsb + s1 * 16384;
    const char* Bs1 = ldsb + 65536 + s1 * 16384;
    bf16x8 af[4], bfr[4];

    // ===== phase 0
#pragma unroll
    for (int i = 0; i < 4; ++i) af[i] = *(const bf16x8*)(As0 + aread[i]);
#pragma unroll
    for (int i = 0; i < 4; ++i) bfr[i] = *(const bf16x8*)(Bs0 + bread[i]);
    STAGE(4 * t + 6);
    bar();
    __builtin_amdgcn_s_setprio(1);
#pragma unroll
    for (int mi = 0; mi < 4; ++mi)
#pragma unroll
      for (int ni = 0; ni < 4; ++ni)
        acc[mi][ni] = __builtin_amdgcn_mfma_f32_16x16x32_bf16(
            af[mi], bfr[ni], acc[mi][ni], 0, 0, 0);
    __builtin_amdgcn_s_setprio(0);
    bar();

    // ===== phase 1
#pragma unroll
    for (int i = 0; i < 4; ++i) af[i] = *(const bf16x8*)(As0 + aread[4 + i]);
    STAGE(4 * t + 7);
    bar();
    __builtin_amdgcn_s_setprio(1);
#pragma unroll
    for (int mi = 0; mi < 4; ++mi)
#pragma unroll
      for (int ni = 0; ni < 4; ++ni)
        acc[4 + mi][ni] = __builtin_amdgcn_mfma_f32_16x16x32_bf16(
            af[mi], bfr[ni], acc[4 + mi][ni], 0, 0, 0);
    __builtin_amdgcn_s_setprio(0);
    bar();

    // ===== phase 2
#pragma unroll
    for (int i = 0; i < 4; ++i) af[i] = *(const bf16x8*)(As1 + aread[i]);
#pragma unroll
    for (int i = 0; i < 4; ++i) bfr[i] = *(const bf16x8*)(Bs1 + bread[i]);
    STAGE(4 * t + 8);
    bar();
    __builtin_amdgcn_s_setprio(1);
#pragma unroll
    for (int mi = 0; mi < 4; ++mi)
#pragma unroll
      for (int ni = 0; ni < 4; ++ni)
        acc[mi][ni] = __builtin_amdgcn_mfma_f32_16x16x32_bf16(
            af[mi], bfr[ni], acc[mi][ni], 0, 0, 0);
    __builtin_amdgcn_s_setprio(0);
    bar();

    // ===== phase 3 + per-tile counted vmcnt
#pragma unroll
    for (int i = 0; i < 4; ++i) af[i] = *(const bf16x8*)(As1 + aread[4 + i]);
    STAGE(4 * t + 9);
    bar();
    __builtin_amdgcn_s_setprio(1);
#pragma unroll
    for (int mi = 0; mi < 4; ++mi)
#pragma unroll
      for (int ni = 0; ni < 4; ++ni)
        acc[4 + mi][ni] = __builtin_amdgcn_mfma_f32_16x16x32_bf16(
            af[mi], bfr[ni], acc[4 + mi][ni], 0, 0, 0);
    __builtin_amdgcn_s_setprio(0);
    if (t < nk - 2)
      asm volatile("s_waitcnt vmcnt(4)" ::: "memory");
    else if (t == nk - 2)
      asm volatile("s_waitcnt vmcnt(0)" ::: "memory");
    bar();
  }

#pragma unroll
  for (int mi = 0; mi < 8; ++mi)
#pragma unroll
    for (int ni = 0; ni < 4; ++ni) {
      int mb = row0 + wm * 128 + mi * 16 + (g << 2);
      int n = col0 + wn * 64 + ni * 16 + q;
#pragma unroll
      for (int r = 0; r < 4; ++r) {
        int m = mb + r;
        float v = acc[mi][ni][r];
        if (OUT_MODE == 0) {
          ((float*)Cout)[(size_t)m * N + n] = v;
        } else {
          int b = m >> 11, s = m & (S_ - 1);
          int h = n >> 7, d = n & (HD_ - 1);
          ((u16*)Cout)[(((size_t)(b * heads + h)) * S_ + s) * HD_ + d] = f2b(v);
        }
      }
    }
}

// ---------------------------------------------------------------------------
// Flash attention. R6 structure + (a) Q-RoPE/scale fused into Q-load,
// (b) v_cvt_pk_bf16_f32 for P/Q packing, (c) defer-max (THR=11.5 log2).
// ---------------------------------------------------------------------------
__global__ __launch_bounds__(256) void attn_mfma(
    const u16* __restrict__ Qb, const u16* __restrict__ Kb,
    const u16* __restrict__ Vt, u16* __restrict__ AO,
    const float* __restrict__ fc, const float* __restrict__ fs) {
  __shared__ u16 Ks[64 * 128];
  __shared__ u16 Vs[128 * 64];
  __shared__ u16 Ps[4][16 * 64];

  const int tid = threadIdx.x, lane = tid & 63, wid = tid >> 6;
  const int wbase = tid & ~63;
  const int pid = blockIdx.x, h = blockIdx.y, b = blockIdx.z;
  const int kvh = h >> 2;
  const int qq = lane & 15, g = lane >> 4;

  const u16* Kbase = Kb + ((size_t)(b * KV_ + kvh) * S_) * HD_;
  const u16* Vbase = Vt + ((size_t)(b * KV_ + kvh) * HD_) * S_;

  const u16* Kl[4];
  const u16* Vl[4];
#pragma unroll
  for (int i = 0; i < 4; ++i) {
    int gg = i * 256 + tid;
    int rK = gg >> 4, ssK = (gg & 15) ^ (rK & 7);
    Kl[i] = Kbase + (size_t)rK * HD_ + ssK * 8;
    int rV = gg >> 3, ssV = (gg & 7) ^ (rV & 7);
    Vl[i] = Vbase + (size_t)rV * S_ + ssV * 8;
  }
  char* const pw = (char*)Ps[wid];

  for (int half = 0; half < 2; ++half) {
    const int qt = half ? (31 - pid) : pid;
    const int q0 = qt * 64;

    // ---- Q load + fused RoPE + SCALE*log2e (pairs are lane-local)
    bf16x8 qf[4];
    {
      const int srow = q0 + wid * 16 + qq;
      const u16* qrow = Qb + ((size_t)(b * H_ + h) * S_ + srow) * HD_ + (g << 3);
      const float* cb = fc + srow * 64 + (g << 2);
      const float* sb = fs + srow * 64 + (g << 2);
#pragma unroll
      for (int ks = 0; ks < 4; ++ks) {
        u16x8 v = *(const u16x8*)(qrow + ks * 32);
        float4 cv = *(const float4*)(cb + ks * 16);
        float4 sv = *(const float4*)(sb + ks * 16);
        unsigned w[4];
#pragma unroll
        for (int j = 0; j < 4; ++j) {
          float c = ((const float*)&cv)[j] * QSCALE_;
          float s = ((const float*)&sv)[j] * QSCALE_;
          float re = b2f((u16)v[2 * j]), im = b2f((u16)v[2 * j + 1]);
          w[j] = cvt_pk_bf16(re * c - im * s, re * s + im * c);
        }
        union { unsigned u[4]; bf16x8 q; } cvt;
        cvt.u[0] = w[0]; cvt.u[1] = w[1]; cvt.u[2] = w[2]; cvt.u[3] = w[3];
        qf[ks] = cvt.q;
      }
    }

    f32x4 oacc[8];
#pragma unroll
    for (int i = 0; i < 8; ++i) oacc[i] = (f32x4){0.f, 0.f, 0.f, 0.f};
    float mrow = -3e38f, lrow = 0.f;

    for (int kt = 0; kt <= qt; ++kt) {
      const int kv0 = kt * 64;
#pragma unroll
      for (int i = 0; i < 4; ++i)
        async_copy16(Kl[i] + (size_t)kv0 * HD_, (char*)Ks + (i * 256 + wbase) * 16);
#pragma unroll
      for (int i = 0; i < 4; ++i)
        async_copy16(Vl[i] + kv0, (char*)Vs + (i * 256 + wbase) * 16);
      __syncthreads();

      // ---- S^T = K Q^T
      f32x4 sacc[4];
#pragma unroll
      for (int nf = 0; nf < 4; ++nf) sacc[nf] = (f32x4){0.f, 0.f, 0.f, 0.f};
#pragma unroll
      for (int nf = 0; nf < 4; ++nf) {
        int r = nf * 16 + qq;
        const char* base = (const char*)Ks + r * 256;
#pragma unroll
        for (int ks = 0; ks < 4; ++ks) {
          int off = (ks * 64 + (g << 4)) ^ ((r & 7) << 4);
          bf16x8 kf = *(const bf16x8*)(base + off);
          sacc[nf] =
              __builtin_amdgcn_mfma_f32_16x16x32_bf16(kf, qf[ks], sacc[nf], 0, 0, 0);
        }
      }

      // ---- in-register online softmax (log2 domain), defer-max
      float rmax = -3e38f;
      if (kt == qt) {
        const int qg = q0 + wid * 16 + qq;
#pragma unroll
        for (int nf = 0; nf < 4; ++nf)
#pragma unroll
          for (int r = 0; r < 4; ++r) {
            int kg = kv0 + nf * 16 + g * 4 + r;
            float sv = (kg > qg) ? -3e38f : sacc[nf][r];
            sacc[nf][r] = sv;
            rmax = fmaxf(rmax, sv);
          }
      } else {
#pragma unroll
        for (int nf = 0; nf < 4; ++nf)
#pragma unroll
          for (int r = 0; r < 4; ++r) rmax = fmaxf(rmax, sacc[nf][r]);
      }
      rmax = fmaxf(rmax, __shfl_xor(rmax, 16, 64));
      rmax = fmaxf(rmax, __shfl_xor(rmax, 32, 64));
      const bool defer = __all(rmax - mrow <= 11.5f);
      float mnew, fsc;
      if (defer) {
        mnew = mrow; fsc = 1.0f;
      } else {
        mnew = fmaxf(mrow, rmax); fsc = exp2f(mrow - mnew);
      }
      mrow = mnew;
      float psum = 0.f;
#pragma unroll
      for (int nf = 0; nf < 4; ++nf)
#pragma unroll
        for (int r = 0; r < 4; ++r) {
          float p = exp2f(sacc[nf][r] - mnew);
          sacc[nf][r] = p;
          psum += p;
        }
      psum += __shfl_xor(psum, 16, 64);
      psum += __shfl_xor(psum, 32, 64);
      lrow = lrow * fsc + psum;

      if (!defer) {
        const float fr0 = __shfl(fsc, g * 4 + 0);
        const float fr1 = __shfl(fsc, g * 4 + 1);
        const float fr2 = __shfl(fsc, g * 4 + 2);
        const float fr3 = __shfl(fsc, g * 4 + 3);
#pragma unroll
        for (int df = 0; df < 8; ++df) {
          oacc[df][0] *= fr0; oacc[df][1] *= fr1;
          oacc[df][2] *= fr2; oacc[df][3] *= fr3;
        }
      }

      // ---- P -> per-wave LDS (HW packed cvt)
#pragma unroll
      for (int nf = 0; nf < 4; ++nf) {
        uint2 pk;
        pk.x = cvt_pk_bf16(sacc[nf][0], sacc[nf][1]);
        pk.y = cvt_pk_bf16(sacc[nf][2], sacc[nf][3]);
        int gran = (nf * 2 + (g >> 1)) ^ (qq & 7);
        *(uint2*)(pw + qq * 128 + gran * 16 + (g & 1) * 8) = pk;
      }

      // ---- O += P @ V
#pragma unroll
      for (int ks = 0; ks < 2; ++ks) {
        int poff = qq * 128 + ((ks * 64 + (g << 4)) ^ ((qq & 7) << 4));
        bf16x8 pf = *(const bf16x8*)(pw + poff);
#pragma unroll
        for (int df = 0; df < 8; ++df) {
          int vr = df * 16 + qq;
          int voff = (ks * 64 + (g << 4)) ^ ((vr & 7) << 4);
          bf16x8 vf = *(const bf16x8*)((const char*)Vs + vr * 128 + voff);
          oacc[df] =
              __builtin_amdgcn_mfma_f32_16x16x32_bf16(pf, vf, oacc[df], 0, 0, 0);
        }
      }
      __syncthreads();
    }

    const float linv = 1.f / lrow;
    const float i0 = __shfl(linv, g * 4 + 0);
    const float i1 = __shfl(linv, g * 4 + 1);
    const float i2 = __shfl(linv, g * 4 + 2);
    const float i3 = __shfl(linv, g * 4 + 3);
    const float inv[4] = {i0, i1, i2, i3};
#pragma unroll
    for (int df = 0; df < 8; ++df)
#pragma unroll
      for (int r = 0; r < 4; ++r) {
        int sq = q0 + wid * 16 + g * 4 + r;
        AO[(size_t)(b * S_ + sq) * (H_ * HD_) + h * HD_ + df * 16 + qq] =
            f2b(oacc[df][r] * inv[r]);
      }
  }
}

// ---------------------------------------------------------------------------
extern "C" void kernel_launch(void* const* d_in, const int* in_sizes, int n_in,
                              void* d_out, int out_size, void* d_ws, size_t ws_size,
                              hipStream_t stream) {
  const float* x  = (const float*)d_in[0];
  const float* wq = (const float*)d_in[1];
  const float* wk = (const float*)d_in[2];
  const float* wv = (const float*)d_in[3];
  const float* wo = (const float*)d_in[4];
  const float* fc = (const float*)d_in[5];
  const float* fs = (const float*)d_in[6];
  float* out = (float*)d_out;

  // Workspace (u16 elements), 160 MiB total — same layout as R3-R6.
  // wkT|wvT are adjacent -> combined [2048][4096]; Kh|Vh adjacent -> K|V groups.
  u16* ws  = (u16*)d_ws;
  u16* wqT = ws;
  u16* VtB = ws;              // alias of wqT region (after wqT last use)
  u16* xb  = ws + 16777216;
  u16* AOb = xb;              // alias of xb region (after xb last use)
  u16* woT = ws + 33554432;
  u16* Qh  = ws + 50331648;
  u16* wkT = ws + 67108864;
  u16* wvT = ws + 71303168;
  u16* Kh  = ws + 75497472;
  u16* Vh  = ws + 79691776;   // == Kh + KVOFF_

  dim3 blk(256);

  cvt_bf16<<<dim3(16384), blk, 0, stream>>>(x, xb, 4194304);
  transpose_cvt<<<dim3(64, 64), blk, 0, stream>>>(wq, wqT, DIM_, H_ * HD_);
  transpose_cvt<<<dim3(16, 64), blk, 0, stream>>>(wk, wkT, DIM_, KV_ * HD_);
  transpose_cvt<<<dim3(16, 64), blk, 0, stream>>>(wv, wvT, DIM_, KV_ * HD_);
  transpose_cvt<<<dim3(64, 64), blk, 0, stream>>>(wo, woT, H_ * HD_, DIM_);

  gemm256<1><<<dim3(16, 16), dim3(512), 0, stream>>>(xb, wqT, Qh, 4096, 4096, 4096, H_);
  // combined K+V projection: N=2048 over contiguous wkT|wvT, 512 blocks = 2/CU
  gemm_bf16<2><<<dim3(16, 32), blk, 0, stream>>>(xb, wkT, Kh, 4096, 2048, 4096, KV_);

  rope_bf16<<<dim3(8192), blk, 0, stream>>>((unsigned*)Kh, fc, fs, 2097152, 1.0f);

  transpose_v<<<dim3(32, 2, 16), blk, 0, stream>>>(Vh, VtB);

  attn_mfma<<<dim3(16, 32, 2), blk, 0, stream>>>(Qh, Kh, VtB, AOb, fc, fs);

  gemm256<0><<<dim3(16, 16), dim3(512), 0, stream>>>(AOb, woT, out, 4096, 4096, 4096, 0);
}

// Round 8
// 515.664 us; speedup vs baseline: 18.9693x; 1.0810x over previous
//
#include <hip/hip_runtime.h>
#include <math.h>

#define B_ 2
#define S_ 2048
#define DIM_ 4096
#define H_ 32
#define KV_ 8
#define HD_ 128
#define SCALE_ 0.08838834764831844f   // 128^-0.5
#define QSCALE_ 0.12751744154254998f  // SCALE_ * log2(e)
#define KVOFF_ 4194304                // B*KV*S*HD elements (K->V group stride)

typedef unsigned short u16;
typedef __attribute__((ext_vector_type(8))) short bf16x8;
typedef __attribute__((ext_vector_type(4))) float f32x4;
typedef __attribute__((ext_vector_type(16))) float f32x16;
typedef __attribute__((ext_vector_type(8))) unsigned short u16x8;
typedef __attribute__((ext_vector_type(4))) unsigned short u16x4;

__device__ __forceinline__ u16 f2b(float f) {  // RNE f32->bf16
  union { float f; unsigned u; } v; v.f = f;
  unsigned r = v.u + 0x7fffu + ((v.u >> 16) & 1u);
  return (u16)(r >> 16);
}
__device__ __forceinline__ float b2f(u16 h) {
  union { unsigned u; float f; } v; v.u = ((unsigned)h) << 16;
  return v.f;
}
// HW packed f32->bf16 (RNE): lo -> bits[15:0], hi -> bits[31:16]
__device__ __forceinline__ unsigned cvt_pk_bf16(float lo, float hi) {
  unsigned r;
  asm("v_cvt_pk_bf16_f32 %0, %1, %2" : "=v"(r) : "v"(lo), "v"(hi));
  return r;
}
// Direct-to-LDS async copy, 16B/lane. LDS dest = wave-uniform base + lane*16.
__device__ __forceinline__ void async_copy16(const void* g, void* l) {
  __builtin_amdgcn_global_load_lds(
      (const __attribute__((address_space(1))) void*)g,
      (__attribute__((address_space(3))) void*)l, 16, 0, 0);
}
// Raw barrier WITH compiler memory fence (no vmcnt drain, unlike __syncthreads)
__device__ __forceinline__ void bar() {
  asm volatile("s_barrier" ::: "memory");
}

// ---------------------------------------------------------------------------
// fp32 -> bf16 bulk convert (vectorized)
// ---------------------------------------------------------------------------
__global__ __launch_bounds__(256) void cvt_bf16(const float* __restrict__ in,
                                                u16* __restrict__ out, int n4) {
  int i = blockIdx.x * 256 + threadIdx.x;
  if (i >= n4) return;
  float4 v = ((const float4*)in)[i];
  u16x4 o; o[0] = f2b(v.x); o[1] = f2b(v.y); o[2] = f2b(v.z); o[3] = f2b(v.w);
  ((u16x4*)out)[i] = o;
}

// ---------------------------------------------------------------------------
// W[K][N] fp32 -> WT[N][K] bf16  (tiled 64x64 via LDS)
// ---------------------------------------------------------------------------
__global__ __launch_bounds__(256) void transpose_cvt(
    const float* __restrict__ W, u16* __restrict__ WT, int K, int N) {
  __shared__ float Ts[64][65];
  const int tid = threadIdx.x;
  const int n0 = blockIdx.x * 64, k0 = blockIdx.y * 64;
#pragma unroll
  for (int p = 0; p < 4; ++p) {
    int r = p * 16 + (tid >> 4), c = (tid & 15) * 4;
    float4 v = *(const float4*)(W + (size_t)(k0 + r) * N + n0 + c);
    Ts[r][c] = v.x; Ts[r][c + 1] = v.y; Ts[r][c + 2] = v.z; Ts[r][c + 3] = v.w;
  }
  __syncthreads();
#pragma unroll
  for (int p = 0; p < 4; ++p) {
    int n = p * 16 + (tid >> 4), kq = (tid & 15) * 4;
    u16x4 o;
    o[0] = f2b(Ts[kq + 0][n]); o[1] = f2b(Ts[kq + 1][n]);
    o[2] = f2b(Ts[kq + 2][n]); o[3] = f2b(Ts[kq + 3][n]);
    *(u16x4*)(WT + (size_t)(n0 + n) * K + k0 + kq) = o;
  }
}

// ---------------------------------------------------------------------------
// V [B*KV][S][HD] bf16 -> Vt [B*KV][HD][S] bf16 (tiled 64x64)
// ---------------------------------------------------------------------------
__global__ __launch_bounds__(256) void transpose_v(const u16* __restrict__ V,
                                                   u16* __restrict__ Vt) {
  __shared__ u16 Ts[64][72];
  const int tid = threadIdx.x;
  const int s0 = blockIdx.x * 64, d0 = blockIdx.y * 64, hb = blockIdx.z;
  const u16* src = V + ((size_t)hb * S_ + s0) * HD_ + d0;
#pragma unroll
  for (int p = 0; p < 2; ++p) {
    int r = p * 32 + (tid >> 3), seg = (tid & 7) * 8;
    u16x8 v = *(const u16x8*)(src + (size_t)r * HD_ + seg);
#pragma unroll
    for (int j = 0; j < 8; ++j) Ts[r][seg + j] = v[j];
  }
  __syncthreads();
  u16* dst = Vt + ((size_t)hb * HD_ + d0) * S_ + s0;
#pragma unroll
  for (int p = 0; p < 2; ++p) {
    int d = p * 32 + (tid >> 3), seg = (tid & 7) * 8;
    u16x8 o;
#pragma unroll
    for (int j = 0; j < 8; ++j) o[j] = Ts[seg + j][d];
    *(u16x8*)(dst + (size_t)d * S_ + seg) = o;
  }
}

// ---------------------------------------------------------------------------
// RoPE in-place on bf16 head-major [BH][S][HD] (used for K only now).
// ---------------------------------------------------------------------------
__global__ __launch_bounds__(256) void rope_bf16(unsigned* __restrict__ T,
                                                 const float* __restrict__ cs,
                                                 const float* __restrict__ sn,
                                                 int total, float scale) {
  int idx = blockIdx.x * 256 + threadIdx.x;
  if (idx >= total) return;
  int i = idx & 63, s = (idx >> 6) & (S_ - 1);
  float c = cs[s * 64 + i], si = sn[s * 64 + i];
  unsigned v = T[idx];
  float re = b2f((u16)(v & 0xffffu)), im = b2f((u16)(v >> 16));
  float ore = (re * c - im * si) * scale, oim = (re * si + im * c) * scale;
  T[idx] = (unsigned)f2b(ore) | ((unsigned)f2b(oim) << 16);
}

// ---------------------------------------------------------------------------
// bf16 MFMA GEMM, m97 structure.
// OUT_MODE 0: fp32 row-major. OUT_MODE 1: bf16 head-major.
// OUT_MODE 2: combined K|V projection (N=2048): heads 0-7 -> K group,
//             heads 8-15 -> V group at +KVOFF_ elements.
// ---------------------------------------------------------------------------
template <int OUT_MODE>
__global__ __launch_bounds__(256) void gemm_bf16(
    const u16* __restrict__ A, const u16* __restrict__ Bt,
    void* __restrict__ Cout, int M, int N, int K, int heads) {
  __shared__ u16 As[128 * 64];
  __shared__ u16 Bs[128 * 64];
  const int tid = threadIdx.x, lane = tid & 63;
  const int wbase = tid & ~63;
  const int row0 = blockIdx.y * 128, col0 = blockIdx.x * 128;
  const int wm = ((tid >> 6) >> 1) * 64, wn = ((tid >> 6) & 1) * 64;

  f32x4 acc[4][4];
#pragma unroll
  for (int i = 0; i < 4; ++i)
#pragma unroll
    for (int j = 0; j < 4; ++j) acc[i][j] = (f32x4){0.f, 0.f, 0.f, 0.f};

  const int nk = K >> 6;
  for (int kt = 0; kt < nk; ++kt) {
    const int k0 = kt << 6;
#pragma unroll
    for (int i = 0; i < 4; ++i) {
      int g = i * 256 + tid;
      int r = g >> 3, ss = (g & 7) ^ (r & 7);
      async_copy16(A + (size_t)(row0 + r) * K + k0 + ss * 8,
                   (char*)As + (i * 256 + wbase) * 16);
    }
#pragma unroll
    for (int i = 0; i < 4; ++i) {
      int g = i * 256 + tid;
      int r = g >> 3, ss = (g & 7) ^ (r & 7);
      async_copy16(Bt + (size_t)(col0 + r) * K + k0 + ss * 8,
                   (char*)Bs + (i * 256 + wbase) * 16);
    }
    __syncthreads();
#pragma unroll
    for (int ks = 0; ks < 2; ++ks) {
      bf16x8 af[4], bf[4];
#pragma unroll
      for (int mi = 0; mi < 4; ++mi) {
        int r = wm + mi * 16 + (lane & 15);
        int off = (ks * 64 + ((lane >> 4) << 4)) ^ ((r & 7) << 4);
        af[mi] = *(const bf16x8*)((const char*)As + r * 128 + off);
      }
#pragma unroll
      for (int ni = 0; ni < 4; ++ni) {
        int r = wn + ni * 16 + (lane & 15);
        int off = (ks * 64 + ((lane >> 4) << 4)) ^ ((r & 7) << 4);
        bf[ni] = *(const bf16x8*)((const char*)Bs + r * 128 + off);
      }
#pragma unroll
      for (int mi = 0; mi < 4; ++mi)
#pragma unroll
        for (int ni = 0; ni < 4; ++ni)
          acc[mi][ni] = __builtin_amdgcn_mfma_f32_16x16x32_bf16(
              af[mi], bf[ni], acc[mi][ni], 0, 0, 0);
    }
    __syncthreads();
  }

#pragma unroll
  for (int mi = 0; mi < 4; ++mi)
#pragma unroll
    for (int ni = 0; ni < 4; ++ni) {
      int mb = row0 + wm + mi * 16 + ((lane >> 4) << 2);
      int n = col0 + wn + ni * 16 + (lane & 15);
#pragma unroll
      for (int r = 0; r < 4; ++r) {
        int m = mb + r;
        float v = acc[mi][ni][r];
        if (OUT_MODE == 0) {
          ((float*)Cout)[(size_t)m * N + n] = v;
        } else if (OUT_MODE == 1) {
          int b = m >> 11, s = m & (S_ - 1);
          int h = n >> 7, d = n & (HD_ - 1);
          ((u16*)Cout)[(((size_t)(b * heads + h)) * S_ + s) * HD_ + d] = f2b(v);
        } else {  // combined K|V
          int b = m >> 11, s = m & (S_ - 1);
          int hh = n >> 7, d = n & (HD_ - 1);
          size_t base = (size_t)(hh >> 3) * KVOFF_;
          ((u16*)Cout)[base + (((size_t)(b * 8 + (hh & 7))) * S_ + s) * HD_ + d] =
              f2b(v);
        }
      }
    }
}

// ---------------------------------------------------------------------------
// 256x256 8-phase bf16 MFMA GEMM (unchanged from R6/R7 — verified).
// ---------------------------------------------------------------------------
template <int OUT_MODE>
__global__ __launch_bounds__(512) void gemm256(
    const u16* __restrict__ A, const u16* __restrict__ Bt,
    void* __restrict__ Cout, int M, int N, int K, int heads) {
  __shared__ u16 lds[65536];  // A: bytes [0,65536), B: [65536,131072)
  char* const ldsb = (char*)lds;
  const int tid = threadIdx.x, lane = tid & 63, wid = tid >> 6;
  const int q = lane & 15, g = lane >> 4;
  const int wm = wid >> 2, wn = wid & 3;
  const int row0 = blockIdx.y * 256, col0 = blockIdx.x * 256;
  const int nk = K >> 6, nh = nk << 2;

  const u16* srcA[2];
  const u16* srcB[2];
#pragma unroll
  for (int u = 0; u < 2; ++u) {
    int j = u * 512 + tid;
    int row = ((j >> 3) << 1) + ((j >> 2) & 1);
    int colg = (j & 3) ^ ((j >> 3) & 3);
    srcA[u] = A + (size_t)(row0 + row) * K + colg * 8;
    srcB[u] = Bt + (size_t)(col0 + row) * K + colg * 8;
  }

  auto STAGE = [&](int h) {
    if (h >= nh) return;
    int tau = h >> 2, ks = (h >> 1) & 1, op = h & 1;
    int slot = (2 * tau + ks) & 3;
    int koff = tau * 64 + ks * 32;
    char* lbase = ldsb + op * 65536 + slot * 16384 + wid * 1024;
#pragma unroll
    for (int u = 0; u < 2; ++u)
      async_copy16((op ? srcB[u] : srcA[u]) + koff, lbase + u * 8192);
  };

  int aread[8], bread[4];
#pragma unroll
  for (int mi = 0; mi < 8; ++mi) {
    int row = wm * 128 + mi * 16 + q;
    aread[mi] = (row >> 1) * 128 + (row & 1) * 64 + ((g ^ ((row >> 1) & 3)) << 4);
  }
#pragma unroll
  for (int ni = 0; ni < 4; ++ni) {
    int row = wn * 64 + ni * 16 + q;
    bread[ni] = (row >> 1) * 128 + (row & 1) * 64 + ((g ^ ((row >> 1) & 3)) << 4);
  }

  f32x4 acc[8][4];
#pragma unroll
  for (int i = 0; i < 8; ++i)
#pragma unroll
    for (int j = 0; j < 4; ++j) acc[i][j] = (f32x4){0.f, 0.f, 0.f, 0.f};

#pragma unroll
  for (int h = 0; h < 6; ++h) STAGE(h);
  asm volatile("s_waitcnt vmcnt(4)" ::: "memory");
  bar();

  for (int t = 0; t < nk; ++t) {
    const int s0 = (2 * t) & 3, s1 = (2 * t + 1) & 3;
    const char* As0 = ldsb + s0 * 16384;
    const char* Bs0 = ldsb + 65536 + s0 * 16384;
    const char* As1 = ldsb + s1 * 16384;
    const char* Bs1 = ldsb + 65536 + s1 * 16384;
    bf16x8 af[4], bfr[4];

    // ===== phase 0
#pragma unroll
    for (int i = 0; i < 4; ++i) af[i] = *(const bf16x8*)(As0 + aread[i]);
#pragma unroll
    for (int i = 0; i < 4; ++i) bfr[i] = *(const bf16x8*)(Bs0 + bread[i]);
    STAGE(4 * t + 6);
    bar();
    __builtin_amdgcn_s_setprio(1);
#pragma unroll
    for (int mi = 0; mi < 4; ++mi)
#pragma unroll
      for (int ni = 0; ni < 4; ++ni)
        acc[mi][ni] = __builtin_amdgcn_mfma_f32_16x16x32_bf16(
            af[mi], bfr[ni], acc[mi][ni], 0, 0, 0);
    __builtin_amdgcn_s_setprio(0);
    bar();

    // ===== phase 1
#pragma unroll
    for (int i = 0; i < 4; ++i) af[i] = *(const bf16x8*)(As0 + aread[4 + i]);
    STAGE(4 * t + 7);
    bar();
    __builtin_amdgcn_s_setprio(1);
#pragma unroll
    for (int mi = 0; mi < 4; ++mi)
#pragma unroll
      for (int ni = 0; ni < 4; ++ni)
        acc[4 + mi][ni] = __builtin_amdgcn_mfma_f32_16x16x32_bf16(
            af[mi], bfr[ni], acc[4 + mi][ni], 0, 0, 0);
    __builtin_amdgcn_s_setprio(0);
    bar();

    // ===== phase 2
#pragma unroll
    for (int i = 0; i < 4; ++i) af[i] = *(const bf16x8*)(As1 + aread[i]);
#pragma unroll
    for (int i = 0; i < 4; ++i) bfr[i] = *(const bf16x8*)(Bs1 + bread[i]);
    STAGE(4 * t + 8);
    bar();
    __builtin_amdgcn_s_setprio(1);
#pragma unroll
    for (int mi = 0; mi < 4; ++mi)
#pragma unroll
      for (int ni = 0; ni < 4; ++ni)
        acc[mi][ni] = __builtin_amdgcn_mfma_f32_16x16x32_bf16(
            af[mi], bfr[ni], acc[mi][ni], 0, 0, 0);
    __builtin_amdgcn_s_setprio(0);
    bar();

    // ===== phase 3 + per-tile counted vmcnt
#pragma unroll
    for (int i = 0; i < 4; ++i) af[i] = *(const bf16x8*)(As1 + aread[4 + i]);
    STAGE(4 * t + 9);
    bar();
    __builtin_amdgcn_s_setprio(1);
#pragma unroll
    for (int mi = 0; mi < 4; ++mi)
#pragma unroll
      for (int ni = 0; ni < 4; ++ni)
        acc[4 + mi][ni] = __builtin_amdgcn_mfma_f32_16x16x32_bf16(
            af[mi], bfr[ni], acc[4 + mi][ni], 0, 0, 0);
    __builtin_amdgcn_s_setprio(0);
    if (t < nk - 2)
      asm volatile("s_waitcnt vmcnt(4)" ::: "memory");
    else if (t == nk - 2)
      asm volatile("s_waitcnt vmcnt(0)" ::: "memory");
    bar();
  }

#pragma unroll
  for (int mi = 0; mi < 8; ++mi)
#pragma unroll
    for (int ni = 0; ni < 4; ++ni) {
      int mb = row0 + wm * 128 + mi * 16 + (g << 2);
      int n = col0 + wn * 64 + ni * 16 + q;
#pragma unroll
      for (int r = 0; r < 4; ++r) {
        int m = mb + r;
        float v = acc[mi][ni][r];
        if (OUT_MODE == 0) {
          ((float*)Cout)[(size_t)m * N + n] = v;
        } else {
          int b = m >> 11, s = m & (S_ - 1);
          int h = n >> 7, d = n & (HD_ - 1);
          ((u16*)Cout)[(((size_t)(b * heads + h)) * S_ + s) * HD_ + d] = f2b(v);
        }
      }
    }
}

// ---------------------------------------------------------------------------
// Flash attention, 32x32x16 MFMA (LDS-traffic-halved vs 16x16x32).
// Wave owns 32 q-rows (QBLK=128/block, 4 waves); KVBLK=64.
// Swapped QK^T: sacc = mfma32(K, Q) = S^T; C layout col=lane&31 (q),
// row=(r&3)+8*(r>>2)+4*(lane>>5) (kv) [HW-verified m74/m101].
// Softmax fully in-register (1 shfl_xor(32) per reduce). P stays in
// REGISTERS via v_cvt_pk_bf16_f32 + v_permlane32_swap_b32 (T12): pairs
// (w0,w2),(w1,w3) swap -> natural word order gives contiguous-k A-frags.
// Q pre-scaled by SCALE*log2e (fused RoPE) -> exp2. Defer-max THR=11.5.
// Grid (8, 32, 2): paired q-tiles {i,15-i} -> uniform 34 kv-tiles/block,
// 512 blocks = 2/CU. LDS 32KB (K 16 + V 16, no P buffer).
// ---------------------------------------------------------------------------
__global__ __launch_bounds__(256, 2) void attn_mfma(
    const u16* __restrict__ Qb, const u16* __restrict__ Kb,
    const u16* __restrict__ Vt, u16* __restrict__ AO,
    const float* __restrict__ fc, const float* __restrict__ fs) {
  __shared__ u16 Ks[64 * 128];  // [kv][d] 256B rows, swizzled
  __shared__ u16 Vs[128 * 64];  // [d][kv] 128B rows, swizzled

  const int tid = threadIdx.x, lane = tid & 63, wid = tid >> 6;
  const int wbase = tid & ~63;
  const int pid = blockIdx.x, h = blockIdx.y, b = blockIdx.z;
  const int kvh = h >> 2;
  const int l31 = lane & 31, hi = lane >> 5;

  const u16* Kbase = Kb + ((size_t)(b * KV_ + kvh) * S_) * HD_;
  const u16* Vbase = Vt + ((size_t)(b * KV_ + kvh) * HD_) * S_;

  const u16* Kl[4];
  const u16* Vl[4];
#pragma unroll
  for (int i = 0; i < 4; ++i) {
    int gg = i * 256 + tid;
    int rK = gg >> 4, ssK = (gg & 15) ^ (rK & 7);
    Kl[i] = Kbase + (size_t)rK * HD_ + ssK * 8;
    int rV = gg >> 3, ssV = (gg & 7) ^ (rV & 7);
    Vl[i] = Vbase + (size_t)rV * S_ + ssV * 8;
  }

  for (int half = 0; half < 2; ++half) {
    const int qt = half ? (15 - pid) : pid;
    const int q0 = qt * 128;
    const int qg = q0 + wid * 32 + l31;  // this lane's q-row

    // ---- Q load + fused RoPE + QSCALE. B-frag: q=lane&31, d=ks*16+hi*8+j
    bf16x8 qf[8];
    {
      const u16* qrow = Qb + ((size_t)(b * H_ + h) * S_ + qg) * HD_ + hi * 8;
      const float* cb = fc + qg * 64 + hi * 4;
      const float* sb = fs + qg * 64 + hi * 4;
#pragma unroll
      for (int ks = 0; ks < 8; ++ks) {
        u16x8 v = *(const u16x8*)(qrow + ks * 16);
        float4 cv = *(const float4*)(cb + ks * 8);
        float4 sv = *(const float4*)(sb + ks * 8);
        unsigned w[4];
#pragma unroll
        for (int j = 0; j < 4; ++j) {
          float c = ((const float*)&cv)[j] * QSCALE_;
          float s = ((const float*)&sv)[j] * QSCALE_;
          float re = b2f((u16)v[2 * j]), im = b2f((u16)v[2 * j + 1]);
          w[j] = cvt_pk_bf16(re * c - im * s, re * s + im * c);
        }
        union { unsigned u[4]; bf16x8 q; } cvt;
        cvt.u[0] = w[0]; cvt.u[1] = w[1]; cvt.u[2] = w[2]; cvt.u[3] = w[3];
        qf[ks] = cvt.q;
      }
    }

    f32x16 oacc[4];
#pragma unroll
    for (int i = 0; i < 4; ++i)
#pragma unroll
      for (int j = 0; j < 16; ++j) oacc[i][j] = 0.f;
    float mrow = -3e38f, lrow = 0.f;

    const int nkt = 2 * qt + 2;
    for (int kt = 0; kt < nkt; ++kt) {
      const int kv0 = kt * 64;
#pragma unroll
      for (int i = 0; i < 4; ++i)
        async_copy16(Kl[i] + (size_t)kv0 * HD_, (char*)Ks + (i * 256 + wbase) * 16);
#pragma unroll
      for (int i = 0; i < 4; ++i)
        async_copy16(Vl[i] + kv0, (char*)Vs + (i * 256 + wbase) * 16);
      __syncthreads();

      // ---- S^T = K Q^T  (2 kv-frags x 8 d-steps)
      f32x16 sacc[2];
#pragma unroll
      for (int kf = 0; kf < 2; ++kf)
#pragma unroll
        for (int j = 0; j < 16; ++j) sacc[kf][j] = 0.f;
#pragma unroll
      for (int ks = 0; ks < 8; ++ks) {
#pragma unroll
        for (int kf = 0; kf < 2; ++kf) {
          const int arow = kf * 32 + l31;
          bf16x8 kfrag = *(const bf16x8*)(
              (const char*)Ks + arow * 256 + ((((ks * 2 + hi) << 4)) ^ ((arow & 7) << 4)));
          sacc[kf] = __builtin_amdgcn_mfma_f32_32x32x16_bf16(kfrag, qf[ks],
                                                             sacc[kf], 0, 0, 0);
        }
      }

      // ---- causal mask (elementwise; wave-uniform condition)
      if (kv0 + 63 > q0 + wid * 32) {
#pragma unroll
        for (int kf = 0; kf < 2; ++kf)
#pragma unroll
          for (int r = 0; r < 16; ++r) {
            int kg = kv0 + kf * 32 + (r & 3) + 8 * (r >> 2) + 4 * hi;
            if (kg > qg) sacc[kf][r] = -3e38f;
          }
      }

      // ---- in-register online softmax (log2 domain), defer-max
      float rmax = -3e38f;
#pragma unroll
      for (int kf = 0; kf < 2; ++kf)
#pragma unroll
        for (int r = 0; r < 16; ++r) rmax = fmaxf(rmax, sacc[kf][r]);
      rmax = fmaxf(rmax, __shfl_xor(rmax, 32, 64));
      const bool defer = __all(rmax - mrow <= 11.5f);
      float mnew, fsc;
      if (defer) {
        mnew = mrow; fsc = 1.0f;
      } else {
        mnew = fmaxf(mrow, rmax); fsc = exp2f(mrow - mnew);
      }
      mrow = mnew;
      float psum = 0.f;
#pragma unroll
      for (int kf = 0; kf < 2; ++kf)
#pragma unroll
        for (int r = 0; r < 16; ++r) {
          float p = exp2f(sacc[kf][r] - mnew);
          sacc[kf][r] = p;
          psum += p;
        }
      psum += __shfl_xor(psum, 32, 64);
      lrow = lrow * fsc + psum;

      if (!defer) {  // rare: redistribute fsc to O rows (q' = crow(r,hi))
#pragma unroll
        for (int r = 0; r < 16; ++r) {
          float fr = __shfl(fsc, (r & 3) + 8 * (r >> 2) + 4 * hi, 64);
#pragma unroll
          for (int df = 0; df < 4; ++df) oacc[df][r] *= fr;
        }
      }

      // ---- P -> registers: cvt_pk pairs + permlane32_swap -> A-frags
      bf16x8 pa[4];
#pragma unroll
      for (int kf = 0; kf < 2; ++kf) {
        unsigned w0 = cvt_pk_bf16(sacc[kf][0], sacc[kf][1]);
        unsigned w1 = cvt_pk_bf16(sacc[kf][2], sacc[kf][3]);
        unsigned w2 = cvt_pk_bf16(sacc[kf][4], sacc[kf][5]);
        unsigned w3 = cvt_pk_bf16(sacc[kf][6], sacc[kf][7]);
        unsigned w4 = cvt_pk_bf16(sacc[kf][8], sacc[kf][9]);
        unsigned w5 = cvt_pk_bf16(sacc[kf][10], sacc[kf][11]);
        unsigned w6 = cvt_pk_bf16(sacc[kf][12], sacc[kf][13]);
        unsigned w7 = cvt_pk_bf16(sacc[kf][14], sacc[kf][15]);
        asm volatile("v_permlane32_swap_b32 %0, %1" : "+v"(w0), "+v"(w2));
        asm volatile("v_permlane32_swap_b32 %0, %1" : "+v"(w1), "+v"(w3));
        asm volatile("v_permlane32_swap_b32 %0, %1" : "+v"(w4), "+v"(w6));
        asm volatile("v_permlane32_swap_b32 %0, %1" : "+v"(w5), "+v"(w7));
        union { unsigned u[4]; bf16x8 q; } f0, f1;
        f0.u[0] = w0; f0.u[1] = w1; f0.u[2] = w2; f0.u[3] = w3;
        f1.u[0] = w4; f1.u[1] = w5; f1.u[2] = w6; f1.u[3] = w7;
        pa[kf * 2] = f0.q;
        pa[kf * 2 + 1] = f1.q;
      }

      // ---- O += P @ V  (4 d-frags x 4 kv-steps)
#pragma unroll
      for (int ks = 0; ks < 4; ++ks) {
#pragma unroll
        for (int df = 0; df < 4; ++df) {
          const int vrow = df * 32 + l31;
          bf16x8 vf = *(const bf16x8*)(
              (const char*)Vs + vrow * 128 + ((((ks * 2 + hi) << 4)) ^ ((vrow & 7) << 4)));
          oacc[df] = __builtin_amdgcn_mfma_f32_32x32x16_bf16(pa[ks], vf,
                                                             oacc[df], 0, 0, 0);
        }
      }
      __syncthreads();
    }

    // ---- epilogue: O[q'][d = df*32+l31]
    const float linv = 1.f / lrow;
#pragma unroll
    for (int r = 0; r < 16; ++r) {
      const int qloc = (r & 3) + 8 * (r >> 2) + 4 * hi;
      const float invq = __shfl(linv, qloc, 64);
      const int sq = q0 + wid * 32 + qloc;
      u16* dst = AO + (size_t)(b * S_ + sq) * (H_ * HD_) + h * HD_ + l31;
#pragma unroll
      for (int df = 0; df < 4; ++df) dst[df * 32] = f2b(oacc[df][r] * invq);
    }
  }
}

// ---------------------------------------------------------------------------
extern "C" void kernel_launch(void* const* d_in, const int* in_sizes, int n_in,
                              void* d_out, int out_size, void* d_ws, size_t ws_size,
                              hipStream_t stream) {
  const float* x  = (const float*)d_in[0];
  const float* wq = (const float*)d_in[1];
  const float* wk = (const float*)d_in[2];
  const float* wv = (const float*)d_in[3];
  const float* wo = (const float*)d_in[4];
  const float* fc = (const float*)d_in[5];
  const float* fs = (const float*)d_in[6];
  float* out = (float*)d_out;

  // Workspace (u16 elements), 160 MiB total — same layout as R3-R7.
  u16* ws  = (u16*)d_ws;
  u16* wqT = ws;
  u16* VtB = ws;              // alias of wqT region (after wqT last use)
  u16* xb  = ws + 16777216;
  u16* AOb = xb;              // alias of xb region (after xb last use)
  u16* woT = ws + 33554432;
  u16* Qh  = ws + 50331648;
  u16* wkT = ws + 67108864;
  u16* wvT = ws + 71303168;
  u16* Kh  = ws + 75497472;
  u16* Vh  = ws + 79691776;   // == Kh + KVOFF_

  dim3 blk(256);

  cvt_bf16<<<dim3(16384), blk, 0, stream>>>(x, xb, 4194304);
  transpose_cvt<<<dim3(64, 64), blk, 0, stream>>>(wq, wqT, DIM_, H_ * HD_);
  transpose_cvt<<<dim3(16, 64), blk, 0, stream>>>(wk, wkT, DIM_, KV_ * HD_);
  transpose_cvt<<<dim3(16, 64), blk, 0, stream>>>(wv, wvT, DIM_, KV_ * HD_);
  transpose_cvt<<<dim3(64, 64), blk, 0, stream>>>(wo, woT, H_ * HD_, DIM_);

  gemm256<1><<<dim3(16, 16), dim3(512), 0, stream>>>(xb, wqT, Qh, 4096, 4096, 4096, H_);
  // combined K+V projection: N=2048 over contiguous wkT|wvT, 512 blocks = 2/CU
  gemm_bf16<2><<<dim3(16, 32), blk, 0, stream>>>(xb, wkT, Kh, 4096, 2048, 4096, KV_);

  rope_bf16<<<dim3(8192), blk, 0, stream>>>((unsigned*)Kh, fc, fs, 2097152, 1.0f);

  transpose_v<<<dim3(32, 2, 16), blk, 0, stream>>>(Vh, VtB);

  attn_mfma<<<dim3(8, 32, 2), blk, 0, stream>>>(Qh, Kh, VtB, AOb, fc, fs);

  gemm256<0><<<dim3(16, 16), dim3(512), 0, stream>>>(AOb, woT, out, 4096, 4096, 4096, 0);
}

// Round 9
// 515.499 us; speedup vs baseline: 18.9754x; 1.0003x over previous
//
#include <hip/hip_runtime.h>
#include <math.h>

#define B_ 2
#define S_ 2048
#define DIM_ 4096
#define H_ 32
#define KV_ 8
#define HD_ 128
#define SCALE_ 0.08838834764831844f   // 128^-0.5
#define QSCALE_ 0.12751744154254998f  // SCALE_ * log2(e)
#define KVOFF_ 4194304                // B*KV*S*HD elements (K->V group stride)

typedef unsigned short u16;
typedef __attribute__((ext_vector_type(8))) short bf16x8;
typedef __attribute__((ext_vector_type(4))) float f32x4;
typedef __attribute__((ext_vector_type(16))) float f32x16;
typedef __attribute__((ext_vector_type(8))) unsigned short u16x8;
typedef __attribute__((ext_vector_type(4))) unsigned short u16x4;

__device__ __forceinline__ u16 f2b(float f) {  // RNE f32->bf16
  union { float f; unsigned u; } v; v.f = f;
  unsigned r = v.u + 0x7fffu + ((v.u >> 16) & 1u);
  return (u16)(r >> 16);
}
__device__ __forceinline__ float b2f(u16 h) {
  union { unsigned u; float f; } v; v.u = ((unsigned)h) << 16;
  return v.f;
}
// HW packed f32->bf16 (RNE): lo -> bits[15:0], hi -> bits[31:16]
__device__ __forceinline__ unsigned cvt_pk_bf16(float lo, float hi) {
  unsigned r;
  asm("v_cvt_pk_bf16_f32 %0, %1, %2" : "=v"(r) : "v"(lo), "v"(hi));
  return r;
}
// Direct-to-LDS async copy, 16B/lane. LDS dest = wave-uniform base + lane*16.
__device__ __forceinline__ void async_copy16(const void* g, void* l) {
  __builtin_amdgcn_global_load_lds(
      (const __attribute__((address_space(1))) void*)g,
      (__attribute__((address_space(3))) void*)l, 16, 0, 0);
}
// Raw barrier WITH compiler memory fence (no vmcnt drain, unlike __syncthreads)
__device__ __forceinline__ void bar() {
  asm volatile("s_barrier" ::: "memory");
}

// ---------------------------------------------------------------------------
// fp32 -> bf16 bulk convert (vectorized)
// ---------------------------------------------------------------------------
__global__ __launch_bounds__(256) void cvt_bf16(const float* __restrict__ in,
                                                u16* __restrict__ out, int n4) {
  int i = blockIdx.x * 256 + threadIdx.x;
  if (i >= n4) return;
  float4 v = ((const float4*)in)[i];
  u16x4 o; o[0] = f2b(v.x); o[1] = f2b(v.y); o[2] = f2b(v.z); o[3] = f2b(v.w);
  ((u16x4*)out)[i] = o;
}

// ---------------------------------------------------------------------------
// W[K][N] fp32 -> WT[N][K] bf16  (tiled 64x64 via LDS)
// ---------------------------------------------------------------------------
__global__ __launch_bounds__(256) void transpose_cvt(
    const float* __restrict__ W, u16* __restrict__ WT, int K, int N) {
  __shared__ float Ts[64][65];
  const int tid = threadIdx.x;
  const int n0 = blockIdx.x * 64, k0 = blockIdx.y * 64;
#pragma unroll
  for (int p = 0; p < 4; ++p) {
    int r = p * 16 + (tid >> 4), c = (tid & 15) * 4;
    float4 v = *(const float4*)(W + (size_t)(k0 + r) * N + n0 + c);
    Ts[r][c] = v.x; Ts[r][c + 1] = v.y; Ts[r][c + 2] = v.z; Ts[r][c + 3] = v.w;
  }
  __syncthreads();
#pragma unroll
  for (int p = 0; p < 4; ++p) {
    int n = p * 16 + (tid >> 4), kq = (tid & 15) * 4;
    u16x4 o;
    o[0] = f2b(Ts[kq + 0][n]); o[1] = f2b(Ts[kq + 1][n]);
    o[2] = f2b(Ts[kq + 2][n]); o[3] = f2b(Ts[kq + 3][n]);
    *(u16x4*)(WT + (size_t)(n0 + n) * K + k0 + kq) = o;
  }
}

// ---------------------------------------------------------------------------
// V [B*KV][S][HD] bf16 -> Vt [B*KV][HD][S] bf16 (tiled 64x64)
// ---------------------------------------------------------------------------
__global__ __launch_bounds__(256) void transpose_v(const u16* __restrict__ V,
                                                   u16* __restrict__ Vt) {
  __shared__ u16 Ts[64][72];
  const int tid = threadIdx.x;
  const int s0 = blockIdx.x * 64, d0 = blockIdx.y * 64, hb = blockIdx.z;
  const u16* src = V + ((size_t)hb * S_ + s0) * HD_ + d0;
#pragma unroll
  for (int p = 0; p < 2; ++p) {
    int r = p * 32 + (tid >> 3), seg = (tid & 7) * 8;
    u16x8 v = *(const u16x8*)(src + (size_t)r * HD_ + seg);
#pragma unroll
    for (int j = 0; j < 8; ++j) Ts[r][seg + j] = v[j];
  }
  __syncthreads();
  u16* dst = Vt + ((size_t)hb * HD_ + d0) * S_ + s0;
#pragma unroll
  for (int p = 0; p < 2; ++p) {
    int d = p * 32 + (tid >> 3), seg = (tid & 7) * 8;
    u16x8 o;
#pragma unroll
    for (int j = 0; j < 8; ++j) o[j] = Ts[seg + j][d];
    *(u16x8*)(dst + (size_t)d * S_ + seg) = o;
  }
}

// ---------------------------------------------------------------------------
// RoPE in-place on bf16 head-major [BH][S][HD] (used for K only now).
// ---------------------------------------------------------------------------
__global__ __launch_bounds__(256) void rope_bf16(unsigned* __restrict__ T,
                                                 const float* __restrict__ cs,
                                                 const float* __restrict__ sn,
                                                 int total, float scale) {
  int idx = blockIdx.x * 256 + threadIdx.x;
  if (idx >= total) return;
  int i = idx & 63, s = (idx >> 6) & (S_ - 1);
  float c = cs[s * 64 + i], si = sn[s * 64 + i];
  unsigned v = T[idx];
  float re = b2f((u16)(v & 0xffffu)), im = b2f((u16)(v >> 16));
  float ore = (re * c - im * si) * scale, oim = (re * si + im * c) * scale;
  T[idx] = (unsigned)f2b(ore) | ((unsigned)f2b(oim) << 16);
}

// ---------------------------------------------------------------------------
// bf16 MFMA GEMM, m97 structure, XCD-swizzled block mapping (T1).
// OUT_MODE 2: combined K|V projection (N=2048): heads 0-7 -> K group,
//             heads 8-15 -> V group at +KVOFF_ elements.
// ---------------------------------------------------------------------------
template <int OUT_MODE>
__global__ __launch_bounds__(256) void gemm_bf16(
    const u16* __restrict__ A, const u16* __restrict__ Bt,
    void* __restrict__ Cout, int M, int N, int K, int heads) {
  __shared__ u16 As[128 * 64];
  __shared__ u16 Bs[128 * 64];
  const int tid = threadIdx.x, lane = tid & 63;
  const int wbase = tid & ~63;
  // XCD swizzle: dispatch o -> work p so each XCD owns contiguous row-panels.
  const int o = blockIdx.y * gridDim.x + blockIdx.x;
  const int q8 = (gridDim.x * gridDim.y) >> 3;  // nwg % 8 == 0 guaranteed
  const int p = (o & 7) * q8 + (o >> 3);
  const int row0 = (p / gridDim.x) * 128, col0 = (p % gridDim.x) * 128;
  const int wm = ((tid >> 6) >> 1) * 64, wn = ((tid >> 6) & 1) * 64;

  f32x4 acc[4][4];
#pragma unroll
  for (int i = 0; i < 4; ++i)
#pragma unroll
    for (int j = 0; j < 4; ++j) acc[i][j] = (f32x4){0.f, 0.f, 0.f, 0.f};

  const int nk = K >> 6;
  for (int kt = 0; kt < nk; ++kt) {
    const int k0 = kt << 6;
#pragma unroll
    for (int i = 0; i < 4; ++i) {
      int g = i * 256 + tid;
      int r = g >> 3, ss = (g & 7) ^ (r & 7);
      async_copy16(A + (size_t)(row0 + r) * K + k0 + ss * 8,
                   (char*)As + (i * 256 + wbase) * 16);
    }
#pragma unroll
    for (int i = 0; i < 4; ++i) {
      int g = i * 256 + tid;
      int r = g >> 3, ss = (g & 7) ^ (r & 7);
      async_copy16(Bt + (size_t)(col0 + r) * K + k0 + ss * 8,
                   (char*)Bs + (i * 256 + wbase) * 16);
    }
    __syncthreads();
#pragma unroll
    for (int ks = 0; ks < 2; ++ks) {
      bf16x8 af[4], bf[4];
#pragma unroll
      for (int mi = 0; mi < 4; ++mi) {
        int r = wm + mi * 16 + (lane & 15);
        int off = (ks * 64 + ((lane >> 4) << 4)) ^ ((r & 7) << 4);
        af[mi] = *(const bf16x8*)((const char*)As + r * 128 + off);
      }
#pragma unroll
      for (int ni = 0; ni < 4; ++ni) {
        int r = wn + ni * 16 + (lane & 15);
        int off = (ks * 64 + ((lane >> 4) << 4)) ^ ((r & 7) << 4);
        bf[ni] = *(const bf16x8*)((const char*)Bs + r * 128 + off);
      }
#pragma unroll
      for (int mi = 0; mi < 4; ++mi)
#pragma unroll
        for (int ni = 0; ni < 4; ++ni)
          acc[mi][ni] = __builtin_amdgcn_mfma_f32_16x16x32_bf16(
              af[mi], bf[ni], acc[mi][ni], 0, 0, 0);
    }
    __syncthreads();
  }

#pragma unroll
  for (int mi = 0; mi < 4; ++mi)
#pragma unroll
    for (int ni = 0; ni < 4; ++ni) {
      int mb = row0 + wm + mi * 16 + ((lane >> 4) << 2);
      int n = col0 + wn + ni * 16 + (lane & 15);
#pragma unroll
      for (int r = 0; r < 4; ++r) {
        int m = mb + r;
        float v = acc[mi][ni][r];
        if (OUT_MODE == 0) {
          ((float*)Cout)[(size_t)m * N + n] = v;
        } else if (OUT_MODE == 1) {
          int b = m >> 11, s = m & (S_ - 1);
          int h = n >> 7, d = n & (HD_ - 1);
          ((u16*)Cout)[(((size_t)(b * heads + h)) * S_ + s) * HD_ + d] = f2b(v);
        } else {  // combined K|V
          int b = m >> 11, s = m & (S_ - 1);
          int hh = n >> 7, d = n & (HD_ - 1);
          size_t base = (size_t)(hh >> 3) * KVOFF_;
          ((u16*)Cout)[base + (((size_t)(b * 8 + (hh & 7))) * S_ + s) * HD_ + d] =
              f2b(v);
        }
      }
    }
}

// ---------------------------------------------------------------------------
// 256x256 8-phase bf16 MFMA GEMM (R6 schedule + T1 XCD swizzle).
// ---------------------------------------------------------------------------
template <int OUT_MODE>
__global__ __launch_bounds__(512) void gemm256(
    const u16* __restrict__ A, const u16* __restrict__ Bt,
    void* __restrict__ Cout, int M, int N, int K, int heads) {
  __shared__ u16 lds[65536];  // A: bytes [0,65536), B: [65536,131072)
  char* const ldsb = (char*)lds;
  const int tid = threadIdx.x, lane = tid & 63, wid = tid >> 6;
  const int q = lane & 15, g = lane >> 4;
  const int wm = wid >> 2, wn = wid & 3;
  // XCD swizzle: each XCD gets 2 contiguous 256-row panels (grid 16x16).
  const int o = blockIdx.y * gridDim.x + blockIdx.x;
  const int q8 = (gridDim.x * gridDim.y) >> 3;
  const int p = (o & 7) * q8 + (o >> 3);
  const int row0 = (p / gridDim.x) * 256, col0 = (p % gridDim.x) * 256;
  const int nk = K >> 6, nh = nk << 2;

  const u16* srcA[2];
  const u16* srcB[2];
#pragma unroll
  for (int u = 0; u < 2; ++u) {
    int j = u * 512 + tid;
    int row = ((j >> 3) << 1) + ((j >> 2) & 1);
    int colg = (j & 3) ^ ((j >> 3) & 3);
    srcA[u] = A + (size_t)(row0 + row) * K + colg * 8;
    srcB[u] = Bt + (size_t)(col0 + row) * K + colg * 8;
  }

  auto STAGE = [&](int h) {
    if (h >= nh) return;
    int tau = h >> 2, ks = (h >> 1) & 1, op = h & 1;
    int slot = (2 * tau + ks) & 3;
    int koff = tau * 64 + ks * 32;
    char* lbase = ldsb + op * 65536 + slot * 16384 + wid * 1024;
#pragma unroll
    for (int u = 0; u < 2; ++u)
      async_copy16((op ? srcB[u] : srcA[u]) + koff, lbase + u * 8192);
  };

  int aread[8], bread[4];
#pragma unroll
  for (int mi = 0; mi < 8; ++mi) {
    int row = wm * 128 + mi * 16 + q;
    aread[mi] = (row >> 1) * 128 + (row & 1) * 64 + ((g ^ ((row >> 1) & 3)) << 4);
  }
#pragma unroll
  for (int ni = 0; ni < 4; ++ni) {
    int row = wn * 64 + ni * 16 + q;
    bread[ni] = (row >> 1) * 128 + (row & 1) * 64 + ((g ^ ((row >> 1) & 3)) << 4);
  }

  f32x4 acc[8][4];
#pragma unroll
  for (int i = 0; i < 8; ++i)
#pragma unroll
    for (int j = 0; j < 4; ++j) acc[i][j] = (f32x4){0.f, 0.f, 0.f, 0.f};

#pragma unroll
  for (int h = 0; h < 6; ++h) STAGE(h);
  asm volatile("s_waitcnt vmcnt(4)" ::: "memory");
  bar();

  for (int t = 0; t < nk; ++t) {
    const int s0 = (2 * t) & 3, s1 = (2 * t + 1) & 3;
    const char* As0 = ldsb + s0 * 16384;
    const char* Bs0 = ldsb + 65536 + s0 * 16384;
    const char* As1 = ldsb + s1 * 16384;
    const char* Bs1 = ldsb + 65536 + s1 * 16384;
    bf16x8 af[4], bfr[4];

    // ===== phase 0
#pragma unroll
    for (int i = 0; i < 4; ++i) af[i] = *(const bf16x8*)(As0 + aread[i]);
#pragma unroll
    for (int i = 0; i < 4; ++i) bfr[i] = *(const bf16x8*)(Bs0 + bread[i]);
    STAGE(4 * t + 6);
    bar();
    __builtin_amdgcn_s_setprio(1);
#pragma unroll
    for (int mi = 0; mi < 4; ++mi)
#pragma unroll
      for (int ni = 0; ni < 4; ++ni)
        acc[mi][ni] = __builtin_amdgcn_mfma_f32_16x16x32_bf16(
            af[mi], bfr[ni], acc[mi][ni], 0, 0, 0);
    __builtin_amdgcn_s_setprio(0);
    bar();

    // ===== phase 1
#pragma unroll
    for (int i = 0; i < 4; ++i) af[i] = *(const bf16x8*)(As0 + aread[4 + i]);
    STAGE(4 * t + 7);
    bar();
    __builtin_amdgcn_s_setprio(1);
#pragma unroll
    for (int mi = 0; mi < 4; ++mi)
#pragma unroll
      for (int ni = 0; ni < 4; ++ni)
        acc[4 + mi][ni] = __builtin_amdgcn_mfma_f32_16x16x32_bf16(
            af[mi], bfr[ni], acc[4 + mi][ni], 0, 0, 0);
    __builtin_amdgcn_s_setprio(0);
    bar();

    // ===== phase 2
#pragma unroll
    for (int i = 0; i < 4; ++i) af[i] = *(const bf16x8*)(As1 + aread[i]);
#pragma unroll
    for (int i = 0; i < 4; ++i) bfr[i] = *(const bf16x8*)(Bs1 + bread[i]);
    STAGE(4 * t + 8);
    bar();
    __builtin_amdgcn_s_setprio(1);
#pragma unroll
    for (int mi = 0; mi < 4; ++mi)
#pragma unroll
      for (int ni = 0; ni < 4; ++ni)
        acc[mi][ni] = __builtin_amdgcn_mfma_f32_16x16x32_bf16(
            af[mi], bfr[ni], acc[mi][ni], 0, 0, 0);
    __builtin_amdgcn_s_setprio(0);
    bar();

    // ===== phase 3 + per-tile counted vmcnt
#pragma unroll
    for (int i = 0; i < 4; ++i) af[i] = *(const bf16x8*)(As1 + aread[4 + i]);
    STAGE(4 * t + 9);
    bar();
    __builtin_amdgcn_s_setprio(1);
#pragma unroll
    for (int mi = 0; mi < 4; ++mi)
#pragma unroll
      for (int ni = 0; ni < 4; ++ni)
        acc[4 + mi][ni] = __builtin_amdgcn_mfma_f32_16x16x32_bf16(
            af[mi], bfr[ni], acc[4 + mi][ni], 0, 0, 0);
    __builtin_amdgcn_s_setprio(0);
    if (t < nk - 2)
      asm volatile("s_waitcnt vmcnt(4)" ::: "memory");
    else if (t == nk - 2)
      asm volatile("s_waitcnt vmcnt(0)" ::: "memory");
    bar();
  }

#pragma unroll
  for (int mi = 0; mi < 8; ++mi)
#pragma unroll
    for (int ni = 0; ni < 4; ++ni) {
      int mb = row0 + wm * 128 + mi * 16 + (g << 2);
      int n = col0 + wn * 64 + ni * 16 + q;
#pragma unroll
      for (int r = 0; r < 4; ++r) {
        int m = mb + r;
        float v = acc[mi][ni][r];
        if (OUT_MODE == 0) {
          ((float*)Cout)[(size_t)m * N + n] = v;
        } else {
          int b = m >> 11, s = m & (S_ - 1);
          int h = n >> 7, d = n & (HD_ - 1);
          ((u16*)Cout)[(((size_t)(b * heads + h)) * S_ + s) * HD_ + d] = f2b(v);
        }
      }
    }
}

// ---------------------------------------------------------------------------
// Flash attention, 32x32x16 MFMA (R8 structure, verified) + T1 XCD swizzle:
// all 8 q-tile blocks of one (h,b) share K/V -> pinned to one XCD's L2 via
// h = o&31 (so dispatch o%8 == h%8 is constant per (h,b) group).
// ---------------------------------------------------------------------------
__global__ __launch_bounds__(256, 2) void attn_mfma(
    const u16* __restrict__ Qb, const u16* __restrict__ Kb,
    const u16* __restrict__ Vt, u16* __restrict__ AO,
    const float* __restrict__ fc, const float* __restrict__ fs) {
  __shared__ u16 Ks[64 * 128];  // [kv][d] 256B rows, swizzled
  __shared__ u16 Vs[128 * 64];  // [d][kv] 128B rows, swizzled

  const int tid = threadIdx.x, lane = tid & 63, wid = tid >> 6;
  const int wbase = tid & ~63;
  // XCD swizzle: o = dispatch id; h=o&31, b=(o>>5)&1, pid=o>>6 (bijective).
  const int o = blockIdx.x + (blockIdx.y << 3) + (blockIdx.z << 8);
  const int pid = o >> 6, h = o & 31, b = (o >> 5) & 1;
  const int kvh = h >> 2;
  const int l31 = lane & 31, hi = lane >> 5;

  const u16* Kbase = Kb + ((size_t)(b * KV_ + kvh) * S_) * HD_;
  const u16* Vbase = Vt + ((size_t)(b * KV_ + kvh) * HD_) * S_;

  const u16* Kl[4];
  const u16* Vl[4];
#pragma unroll
  for (int i = 0; i < 4; ++i) {
    int gg = i * 256 + tid;
    int rK = gg >> 4, ssK = (gg & 15) ^ (rK & 7);
    Kl[i] = Kbase + (size_t)rK * HD_ + ssK * 8;
    int rV = gg >> 3, ssV = (gg & 7) ^ (rV & 7);
    Vl[i] = Vbase + (size_t)rV * S_ + ssV * 8;
  }

  for (int half = 0; half < 2; ++half) {
    const int qt = half ? (15 - pid) : pid;
    const int q0 = qt * 128;
    const int qg = q0 + wid * 32 + l31;  // this lane's q-row

    // ---- Q load + fused RoPE + QSCALE. B-frag: q=lane&31, d=ks*16+hi*8+j
    bf16x8 qf[8];
    {
      const u16* qrow = Qb + ((size_t)(b * H_ + h) * S_ + qg) * HD_ + hi * 8;
      const float* cb = fc + qg * 64 + hi * 4;
      const float* sb = fs + qg * 64 + hi * 4;
#pragma unroll
      for (int ks = 0; ks < 8; ++ks) {
        u16x8 v = *(const u16x8*)(qrow + ks * 16);
        float4 cv = *(const float4*)(cb + ks * 8);
        float4 sv = *(const float4*)(sb + ks * 8);
        unsigned w[4];
#pragma unroll
        for (int j = 0; j < 4; ++j) {
          float c = ((const float*)&cv)[j] * QSCALE_;
          float s = ((const float*)&sv)[j] * QSCALE_;
          float re = b2f((u16)v[2 * j]), im = b2f((u16)v[2 * j + 1]);
          w[j] = cvt_pk_bf16(re * c - im * s, re * s + im * c);
        }
        union { unsigned u[4]; bf16x8 q; } cvt;
        cvt.u[0] = w[0]; cvt.u[1] = w[1]; cvt.u[2] = w[2]; cvt.u[3] = w[3];
        qf[ks] = cvt.q;
      }
    }

    f32x16 oacc[4];
#pragma unroll
    for (int i = 0; i < 4; ++i)
#pragma unroll
      for (int j = 0; j < 16; ++j) oacc[i][j] = 0.f;
    float mrow = -3e38f, lrow = 0.f;

    const int nkt = 2 * qt + 2;
    for (int kt = 0; kt < nkt; ++kt) {
      const int kv0 = kt * 64;
#pragma unroll
      for (int i = 0; i < 4; ++i)
        async_copy16(Kl[i] + (size_t)kv0 * HD_, (char*)Ks + (i * 256 + wbase) * 16);
#pragma unroll
      for (int i = 0; i < 4; ++i)
        async_copy16(Vl[i] + kv0, (char*)Vs + (i * 256 + wbase) * 16);
      __syncthreads();

      // ---- S^T = K Q^T  (2 kv-frags x 8 d-steps)
      f32x16 sacc[2];
#pragma unroll
      for (int kf = 0; kf < 2; ++kf)
#pragma unroll
        for (int j = 0; j < 16; ++j) sacc[kf][j] = 0.f;
#pragma unroll
      for (int ks = 0; ks < 8; ++ks) {
#pragma unroll
        for (int kf = 0; kf < 2; ++kf) {
          const int arow = kf * 32 + l31;
          bf16x8 kfrag = *(const bf16x8*)(
              (const char*)Ks + arow * 256 + ((((ks * 2 + hi) << 4)) ^ ((arow & 7) << 4)));
          sacc[kf] = __builtin_amdgcn_mfma_f32_32x32x16_bf16(kfrag, qf[ks],
                                                             sacc[kf], 0, 0, 0);
        }
      }

      // ---- causal mask (elementwise; wave-uniform condition)
      if (kv0 + 63 > q0 + wid * 32) {
#pragma unroll
        for (int kf = 0; kf < 2; ++kf)
#pragma unroll
          for (int r = 0; r < 16; ++r) {
            int kg = kv0 + kf * 32 + (r & 3) + 8 * (r >> 2) + 4 * hi;
            if (kg > qg) sacc[kf][r] = -3e38f;
          }
      }

      // ---- in-register online softmax (log2 domain), defer-max
      float rmax = -3e38f;
#pragma unroll
      for (int kf = 0; kf < 2; ++kf)
#pragma unroll
        for (int r = 0; r < 16; ++r) rmax = fmaxf(rmax, sacc[kf][r]);
      rmax = fmaxf(rmax, __shfl_xor(rmax, 32, 64));
      const bool defer = __all(rmax - mrow <= 11.5f);
      float mnew, fsc;
      if (defer) {
        mnew = mrow; fsc = 1.0f;
      } else {
        mnew = fmaxf(mrow, rmax); fsc = exp2f(mrow - mnew);
      }
      mrow = mnew;
      float psum = 0.f;
#pragma unroll
      for (int kf = 0; kf < 2; ++kf)
#pragma unroll
        for (int r = 0; r < 16; ++r) {
          float p = exp2f(sacc[kf][r] - mnew);
          sacc[kf][r] = p;
          psum += p;
        }
      psum += __shfl_xor(psum, 32, 64);
      lrow = lrow * fsc + psum;

      if (!defer) {  // rare: redistribute fsc to O rows (q' = crow(r,hi))
#pragma unroll
        for (int r = 0; r < 16; ++r) {
          float fr = __shfl(fsc, (r & 3) + 8 * (r >> 2) + 4 * hi, 64);
#pragma unroll
          for (int df = 0; df < 4; ++df) oacc[df][r] *= fr;
        }
      }

      // ---- P -> registers: cvt_pk pairs + permlane32_swap -> A-frags
      bf16x8 pa[4];
#pragma unroll
      for (int kf = 0; kf < 2; ++kf) {
        unsigned w0 = cvt_pk_bf16(sacc[kf][0], sacc[kf][1]);
        unsigned w1 = cvt_pk_bf16(sacc[kf][2], sacc[kf][3]);
        unsigned w2 = cvt_pk_bf16(sacc[kf][4], sacc[kf][5]);
        unsigned w3 = cvt_pk_bf16(sacc[kf][6], sacc[kf][7]);
        unsigned w4 = cvt_pk_bf16(sacc[kf][8], sacc[kf][9]);
        unsigned w5 = cvt_pk_bf16(sacc[kf][10], sacc[kf][11]);
        unsigned w6 = cvt_pk_bf16(sacc[kf][12], sacc[kf][13]);
        unsigned w7 = cvt_pk_bf16(sacc[kf][14], sacc[kf][15]);
        asm volatile("v_permlane32_swap_b32 %0, %1" : "+v"(w0), "+v"(w2));
        asm volatile("v_permlane32_swap_b32 %0, %1" : "+v"(w1), "+v"(w3));
        asm volatile("v_permlane32_swap_b32 %0, %1" : "+v"(w4), "+v"(w6));
        asm volatile("v_permlane32_swap_b32 %0, %1" : "+v"(w5), "+v"(w7));
        union { unsigned u[4]; bf16x8 q; } f0, f1;
        f0.u[0] = w0; f0.u[1] = w1; f0.u[2] = w2; f0.u[3] = w3;
        f1.u[0] = w4; f1.u[1] = w5; f1.u[2] = w6; f1.u[3] = w7;
        pa[kf * 2] = f0.q;
        pa[kf * 2 + 1] = f1.q;
      }

      // ---- O += P @ V  (4 d-frags x 4 kv-steps)
#pragma unroll
      for (int ks = 0; ks < 4; ++ks) {
#pragma unroll
        for (int df = 0; df < 4; ++df) {
          const int vrow = df * 32 + l31;
          bf16x8 vf = *(const bf16x8*)(
              (const char*)Vs + vrow * 128 + ((((ks * 2 + hi) << 4)) ^ ((vrow & 7) << 4)));
          oacc[df] = __builtin_amdgcn_mfma_f32_32x32x16_bf16(pa[ks], vf,
                                                             oacc[df], 0, 0, 0);
        }
      }
      __syncthreads();
    }

    // ---- epilogue: O[q'][d = df*32+l31]
    const float linv = 1.f / lrow;
#pragma unroll
    for (int r = 0; r < 16; ++r) {
      const int qloc = (r & 3) + 8 * (r >> 2) + 4 * hi;
      const float invq = __shfl(linv, qloc, 64);
      const int sq = q0 + wid * 32 + qloc;
      u16* dst = AO + (size_t)(b * S_ + sq) * (H_ * HD_) + h * HD_ + l31;
#pragma unroll
      for (int df = 0; df < 4; ++df) dst[df * 32] = f2b(oacc[df][r] * invq);
    }
  }
}

// ---------------------------------------------------------------------------
extern "C" void kernel_launch(void* const* d_in, const int* in_sizes, int n_in,
                              void* d_out, int out_size, void* d_ws, size_t ws_size,
                              hipStream_t stream) {
  const float* x  = (const float*)d_in[0];
  const float* wq = (const float*)d_in[1];
  const float* wk = (const float*)d_in[2];
  const float* wv = (const float*)d_in[3];
  const float* wo = (const float*)d_in[4];
  const float* fc = (const float*)d_in[5];
  const float* fs = (const float*)d_in[6];
  float* out = (float*)d_out;

  // Workspace (u16 elements), 160 MiB total — same layout as R3-R8.
  u16* ws  = (u16*)d_ws;
  u16* wqT = ws;
  u16* VtB = ws;              // alias of wqT region (after wqT last use)
  u16* xb  = ws + 16777216;
  u16* AOb = xb;              // alias of xb region (after xb last use)
  u16* woT = ws + 33554432;
  u16* Qh  = ws + 50331648;
  u16* wkT = ws + 67108864;
  u16* wvT = ws + 71303168;
  u16* Kh  = ws + 75497472;
  u16* Vh  = ws + 79691776;   // == Kh + KVOFF_

  dim3 blk(256);

  cvt_bf16<<<dim3(16384), blk, 0, stream>>>(x, xb, 4194304);
  transpose_cvt<<<dim3(64, 64), blk, 0, stream>>>(wq, wqT, DIM_, H_ * HD_);
  transpose_cvt<<<dim3(16, 64), blk, 0, stream>>>(wk, wkT, DIM_, KV_ * HD_);
  transpose_cvt<<<dim3(16, 64), blk, 0, stream>>>(wv, wvT, DIM_, KV_ * HD_);
  transpose_cvt<<<dim3(64, 64), blk, 0, stream>>>(wo, woT, H_ * HD_, DIM_);

  gemm256<1><<<dim3(16, 16), dim3(512), 0, stream>>>(xb, wqT, Qh, 4096, 4096, 4096, H_);
  // combined K+V projection: N=2048 over contiguous wkT|wvT, 512 blocks = 2/CU
  gemm_bf16<2><<<dim3(16, 32), blk, 0, stream>>>(xb, wkT, Kh, 4096, 2048, 4096, KV_);

  rope_bf16<<<dim3(8192), blk, 0, stream>>>((unsigned*)Kh, fc, fs, 2097152, 1.0f);

  transpose_v<<<dim3(32, 2, 16), blk, 0, stream>>>(Vh, VtB);

  attn_mfma<<<dim3(8, 32, 2), blk, 0, stream>>>(Qh, Kh, VtB, AOb, fc, fs);

  gemm256<0><<<dim3(16, 16), dim3(512), 0, stream>>>(AOb, woT, out, 4096, 4096, 4096, 0);
}